// Round 1
// baseline (557.503 us; speedup 1.0000x reference)
//
#include <hip/hip_runtime.h>

typedef __attribute__((ext_vector_type(4))) float f32x4;
typedef __attribute__((ext_vector_type(8))) short bf16x8;

__device__ __forceinline__ unsigned short f32_to_bf16_rne(float f){
  unsigned u = __builtin_bit_cast(unsigned, f);
  unsigned r = u + 0x7FFFu + ((u >> 16) & 1u);
  return (unsigned short)(r >> 16);
}
__device__ __forceinline__ float bf16_hi_to_f32(unsigned short h){
  unsigned u = ((unsigned)h) << 16;
  return __builtin_bit_cast(float, u);
}
__device__ __forceinline__ float leakyf(float v){ return v > 0.f ? v : 0.01f*v; }
__device__ __forceinline__ unsigned f32_ord(float f){
  unsigned u = __builtin_bit_cast(unsigned, f);
  return (u & 0x80000000u) ? ~u : (u | 0x80000000u);
}

// ---------------- weight pre-split into MFMA B-fragment layout (hi/lo bf16) -------------
// B[k][j] fragment: lane = 16*((k%32)/8) + (j%16), elem = k%8, chunk = (k/32, j/16)
__global__ void prep_w_kernel(const float* __restrict__ W, short* __restrict__ Wh,
                              short* __restrict__ Wl, int K, int N)
{
  int total = K*N;
  int NF = N >> 4;
  for (int i = blockIdx.x*blockDim.x + threadIdx.x; i < total; i += gridDim.x*blockDim.x){
    int k = i / N, n = i % N;
    float w = W[i];
    unsigned short h = f32_to_bf16_rne(w);
    unsigned short l = f32_to_bf16_rne(w - bf16_hi_to_f32(h));
    int kb = k >> 5, kr = k & 31, cb = n >> 4;
    int lanei = ((kr >> 3) << 4) | (n & 15);
    size_t dst = (((size_t)(kb*NF + cb))*64 + lanei)*8 + (kr & 7);
    Wh[dst] = (short)h; Wl[dst] = (short)l;
  }
}

// ---------------- edge pass: histograms + per-edge edge-weights -------------------------
__global__ void edge_pass_kernel(const int* __restrict__ ei, const float* __restrict__ ea,
                                 const float* __restrict__ We0, const float* __restrict__ be0,
                                 const float* __restrict__ We1, const float* __restrict__ be1,
                                 float* __restrict__ w0, float* __restrict__ w1,
                                 int* __restrict__ cnt_row0, int* __restrict__ cnt_row1,
                                 int* __restrict__ cnt_col, int E)
{
  float A0[12], A1[12];
#pragma unroll
  for (int i=0;i<12;i++){ A0[i]=We0[i]; A1[i]=We1[i]; }
  float b0 = be0[0], b1 = be1[0];
  for (int e = blockIdx.x*blockDim.x + threadIdx.x; e < E; e += gridDim.x*blockDim.x){
    int r = ei[e], c = ei[E+e];
    atomicAdd(&cnt_row0[r], 1);
    atomicAdd(&cnt_col[c], 1);
    if ((r>>1) != (c>>1)) atomicAdd(&cnt_row1[r>>1], 1);
    const float* ap = ea + (size_t)e*12;
    float s0 = b0, s1 = b1;
#pragma unroll
    for (int i=0;i<12;i++){ float v = ap[i]; s0 += v*A0[i]; s1 += v*A1[i]; }
    w0[e] = s0; w1[e] = s1;
  }
}

__global__ void dis_kernel(const int* __restrict__ cnt, float* __restrict__ dis, int n)
{
  for (int i = blockIdx.x*blockDim.x + threadIdx.x; i < n; i += gridDim.x*blockDim.x)
    dis[i] = rsqrtf((float)cnt[i] + 1.0f);
}

// ---------------- single-block exclusive scan over cnt_col -> starts/cursor -------------
__global__ __launch_bounds__(1024) void scan_kernel(const int* __restrict__ cnt,
                                                    int* __restrict__ starts,
                                                    int* __restrict__ cursor, int N)
{
  __shared__ int wsum[16];
  __shared__ int carry;
  int t = threadIdx.x;
  int lane = t & 63, wv = t >> 6;
  if (t == 0){ carry = 0; starts[0] = 0; }
  __syncthreads();
  for (int base = 0; base < N; base += 1024){
    int i = base + t;
    int v = (i < N) ? cnt[i] : 0;
    int x = v;
#pragma unroll
    for (int d = 1; d < 64; d <<= 1){
      int y = __shfl_up(x, d);
      if (lane >= d) x += y;
    }
    if (lane == 63) wsum[wv] = x;
    __syncthreads();
    if (t < 16){
      int z = wsum[t];
#pragma unroll
      for (int d = 1; d < 16; d <<= 1){
        int u = __shfl_up(z, d);
        if (t >= d) z += u;
      }
      wsum[t] = z;
    }
    __syncthreads();
    int woff = (wv ? wsum[wv-1] : 0) + carry;
    if (i < N){
      starts[i+1] = woff + x;
      cursor[i]   = woff + x - v;
    }
    __syncthreads();
    if (t == 0) carry += wsum[15];
    __syncthreads();
  }
}

// ---------------- CSR fill with packed payload (row, dis0[row]*w0, dis1[row/2]*w1) ------
__global__ void fill_kernel(const int* __restrict__ ei, const float* __restrict__ w0,
                            const float* __restrict__ w1, const float* __restrict__ dis0,
                            const float* __restrict__ dis1, int* __restrict__ cursor,
                            int* __restrict__ rs, float* __restrict__ c0s,
                            float* __restrict__ c1s, int E)
{
  for (int e = blockIdx.x*blockDim.x + threadIdx.x; e < E; e += gridDim.x*blockDim.x){
    int r = ei[e], c = ei[E+e];
    int pos = atomicAdd(&cursor[c], 1);
    rs[pos]  = r;
    c0s[pos] = dis0[r] * w0[e];
    c1s[pos] = dis1[r>>1] * w1[e];
  }
}

// ---------------- split-bf16 MFMA GEMM: Y = epilogue(X @ W + b) -------------------------
// X: M x K (f32 row-major). W pre-split (hi/lo) in B-frag layout. Y: M x (NF*16) f32.
// flags&1: y = leaky(y*scale + shift)
template<int NF>
__global__ __launch_bounds__(256) void gemm_split(
    const float* __restrict__ X, const short* __restrict__ Wh, const short* __restrict__ Wl,
    const float* __restrict__ bias, const float* __restrict__ scale, const float* __restrict__ shift,
    float* __restrict__ Y, int M, int K, int flags)
{
  const int Nn = NF*16;
  int w = threadIdx.x >> 6, lane = threadIdx.x & 63;
  int r0 = blockIdx.x*64 + w*16;
  int arow = r0 + (lane & 15);
  long arow_c = (arow < M) ? arow : (M-1);
  int kHi = (lane >> 4) << 3;
  f32x4 acc[NF];
#pragma unroll
  for (int i=0;i<NF;i++){
#pragma unroll
    for (int j=0;j<4;j++) acc[i][j] = 0.f;
  }
  int KB = K >> 5;
  const float* aprow = X + arow_c*(long)K + kHi;
  for (int kb=0; kb<KB; ++kb){
    const float* ap = aprow + kb*32;
    f32x4 a0 = *(const f32x4*)ap;
    f32x4 a1 = *(const f32x4*)(ap+4);
    bf16x8 ah, al;
#pragma unroll
    for (int j=0;j<8;j++){
      float f = (j<4) ? a0[j] : a1[j-4];
      unsigned short h = f32_to_bf16_rne(f);
      ah[j] = (short)h;
      al[j] = (short)f32_to_bf16_rne(f - bf16_hi_to_f32(h));
    }
    const short* bp  = Wh + ((size_t)kb*NF*64 + lane)*8;
    const short* bpl = Wl + ((size_t)kb*NF*64 + lane)*8;
#pragma unroll
    for (int cb=0; cb<NF; ++cb){
      bf16x8 bh = *(const bf16x8*)(bp  + (size_t)cb*512);
      bf16x8 bl = *(const bf16x8*)(bpl + (size_t)cb*512);
      acc[cb] = __builtin_amdgcn_mfma_f32_16x16x32_bf16(ah, bh, acc[cb], 0,0,0);
      acc[cb] = __builtin_amdgcn_mfma_f32_16x16x32_bf16(al, bh, acc[cb], 0,0,0);
      acc[cb] = __builtin_amdgcn_mfma_f32_16x16x32_bf16(ah, bl, acc[cb], 0,0,0);
    }
  }
  int crow = r0 + ((lane >> 4) << 2);
  int ccol = lane & 15;
#pragma unroll
  for (int cb=0; cb<NF; ++cb){
    int c = cb*16 + ccol;
    float b = bias[c];
    float sc = 1.f, sh = 0.f;
    if (flags & 1){ sc = scale[c]; sh = shift[c]; }
#pragma unroll
    for (int r=0;r<4;r++){
      int row = crow + r;
      if (row < M){
        float v = acc[cb][r] + b;
        if (flags & 1){ v = v*sc + sh; v = leakyf(v); }
        Y[(size_t)row*Nn + c] = v;
      }
    }
  }
}

// ---------------- layer-0 aggregate: one wave per node ---------------------------------
// out[n] = leaky( dn * sum_{e:col=n} c0s*h0[row] + dn^2*wself*h0[n] + origin[n] )
__global__ __launch_bounds__(256) void mp0_kernel(
    const int* __restrict__ starts, const int* __restrict__ rs, const float* __restrict__ c0s,
    const float* __restrict__ dis0, const float* __restrict__ h0, const float* __restrict__ origin,
    const float* __restrict__ We, const float* __restrict__ be, float* __restrict__ out, int N)
{
  int n = blockIdx.x*4 + (threadIdx.x >> 6);
  if (n >= N) return;
  int lane = threadIdx.x & 63;
  float wself = be[0];
#pragma unroll
  for (int i=0;i<12;i++) wself += We[i];
  int s = starts[n], e = starts[n+1];
  float dn = dis0[n];
  float ax = 0.f, ay = 0.f;
  for (int idx = s; idx < e; ++idx){
    int r = rs[idx];
    float cf = c0s[idx];
    const float2 v = *(const float2*)(h0 + (size_t)r*128 + lane*2);
    ax += cf * v.x; ay += cf * v.y;
  }
  float cs = dn*dn*wself;
  const float2 hv = *(const float2*)(h0 + (size_t)n*128 + lane*2);
  const float2 og = *(const float2*)(origin + (size_t)n*128 + lane*2);
  float ox = leakyf(dn*ax + cs*hv.x + og.x);
  float oy = leakyf(dn*ay + cs*hv.y + og.y);
  float2 o2 = {ox, oy};
  *(float2*)(out + (size_t)n*128 + lane*2) = o2;
}

// ---------------- pair pool: xp[j] = max(h[2j], h[2j+1]) -------------------------------
__global__ void pool_kernel(const float* __restrict__ h, float* __restrict__ xp, int n4)
{
  for (int i = blockIdx.x*blockDim.x + threadIdx.x; i < n4; i += gridDim.x*blockDim.x){
    int j = i >> 5, c4 = i & 31;
    const f32x4 a = *(const f32x4*)(h + ((size_t)(2*j))*128 + c4*4);
    const f32x4 b = *(const f32x4*)(h + ((size_t)(2*j+1))*128 + c4*4);
    f32x4 m;
#pragma unroll
    for (int q=0;q<4;q++) m[q] = fmaxf(a[q], b[q]);
    *(f32x4*)(xp + (size_t)j*128 + c4*4) = m;
  }
}

// ---------------- layer-1 aggregate + global max pool ----------------------------------
__global__ __launch_bounds__(256) void mp1_kernel(
    const int* __restrict__ starts, const int* __restrict__ rs, const float* __restrict__ c1s,
    const float* __restrict__ dis1, const float* __restrict__ h1m,
    const float* __restrict__ We, const float* __restrict__ be,
    const int* __restrict__ batch_p, unsigned* __restrict__ genc, int N2)
{
  int n = blockIdx.x*4 + (threadIdx.x >> 6);
  if (n >= N2) return;
  int lane = threadIdx.x & 63;
  float wself = be[0];
#pragma unroll
  for (int i=0;i<12;i++) wself += We[i];
  int s = starts[2*n], e = starts[2*n+2];
  float dn = dis1[n];
  float ax = 0.f, ay = 0.f;
  for (int idx = s; idx < e; ++idx){
    int r = rs[idx];
    int rp = r >> 1;
    if (rp == n) continue;
    float cf = c1s[idx];
    const float2 v = *(const float2*)(h1m + (size_t)rp*128 + lane*2);
    ax += cf * v.x; ay += cf * v.y;
  }
  float cs = dn*dn*wself;
  const float2 hv = *(const float2*)(h1m + (size_t)n*128 + lane*2);
  float ox = leakyf(dn*ax + cs*hv.x);
  float oy = leakyf(dn*ay + cs*hv.y);
  int b = batch_p[n];
  atomicMax(&genc[(size_t)b*128 + lane*2    ], f32_ord(ox));
  atomicMax(&genc[(size_t)b*128 + lane*2 + 1], f32_ord(oy));
}

// ---------------- head MLP: [64,128] -> [64,64] -> [64] --------------------------------
__global__ __launch_bounds__(256) void head_kernel(
    const unsigned* __restrict__ genc, const float* __restrict__ W1, const float* __restrict__ b1,
    const float* __restrict__ s, const float* __restrict__ t,
    const float* __restrict__ W2, const float* __restrict__ b2, float* __restrict__ out)
{
  __shared__ float g[64][128];
  __shared__ float hh[64][64];
  int tid = threadIdx.x;
  for (int i = tid; i < 64*128; i += 256){
    unsigned u = genc[i];
    unsigned bits = (u & 0x80000000u) ? (u & 0x7FFFFFFFu) : ~u;
    g[i>>7][i&127] = __builtin_bit_cast(float, bits);
  }
  __syncthreads();
  int c = tid & 63;
  int q0 = tid >> 6;          // 0..3 -> rows q0*16 .. q0*16+15
  float accv[16];
#pragma unroll
  for (int i=0;i<16;i++) accv[i] = 0.f;
  for (int k=0;k<128;k++){
    float wv = W1[k*64 + c];
#pragma unroll
    for (int i=0;i<16;i++) accv[i] += g[q0*16+i][k] * wv;
  }
  float sc = s[c], sh = t[c], bb = b1[c];
#pragma unroll
  for (int i=0;i<16;i++){
    float v = (accv[i] + bb)*sc + sh;
    hh[q0*16+i][c] = leakyf(v);
  }
  __syncthreads();
  if (tid < 64){
    float a = b2[0];
    for (int k=0;k<64;k++) a += hh[tid][k]*W2[k];
    out[tid] = a;
  }
}

extern "C" void kernel_launch(void* const* d_in, const int* in_sizes, int n_in,
                              void* d_out, int out_size, void* d_ws, size_t ws_size,
                              hipStream_t stream)
{
  const float* x      = (const float*)d_in[0];
  const float* origin = (const float*)d_in[1];
  const float* ea     = (const float*)d_in[2];
  const int*   ei     = (const int*)d_in[3];
  const int*   batchp = (const int*)d_in[5];
  const float* l0_W1 = (const float*)d_in[6];
  const float* l0_b1 = (const float*)d_in[7];
  const float* l0_s  = (const float*)d_in[8];
  const float* l0_t  = (const float*)d_in[9];
  const float* l0_W2 = (const float*)d_in[10];
  const float* l0_b2 = (const float*)d_in[11];
  const float* l0_We = (const float*)d_in[12];
  const float* l0_be = (const float*)d_in[13];
  const float* l1_W1 = (const float*)d_in[14];
  const float* l1_b1 = (const float*)d_in[15];
  const float* l1_s  = (const float*)d_in[16];
  const float* l1_t  = (const float*)d_in[17];
  const float* l1_W2 = (const float*)d_in[18];
  const float* l1_b2 = (const float*)d_in[19];
  const float* l1_We = (const float*)d_in[20];
  const float* l1_be = (const float*)d_in[21];
  const float* hd_W1 = (const float*)d_in[22];
  const float* hd_b1 = (const float*)d_in[23];
  const float* hd_s  = (const float*)d_in[24];
  const float* hd_t  = (const float*)d_in[25];
  const float* hd_W2 = (const float*)d_in[26];
  const float* hd_b2 = (const float*)d_in[27];

  const int N  = in_sizes[0] / 128;   // 50000
  const int E  = in_sizes[2] / 12;    // 800000
  const int N2 = in_sizes[5];         // 25000
  const int G  = out_size;            // 64

  char* ws = (char*)d_ws;
  size_t off = 0;
  auto alloc = [&](size_t b){ size_t o = off; off += (b + 255) & ~(size_t)255; return o; };
  size_t oA   = alloc((size_t)N*128*4);      // REG_A: hmid0 / hL0 / hmid1
  size_t oB   = alloc((size_t)N*128*4);      // REG_B: h0 ; later xp | h1m
  size_t oW0  = alloc((size_t)E*4);
  size_t oW1  = alloc((size_t)E*4);
  size_t oRS  = alloc((size_t)E*4);          // packed rows
  size_t oC0  = alloc((size_t)E*4);          // packed coef layer0
  size_t oC1  = alloc((size_t)E*4);          // packed coef layer1
  size_t oST  = alloc((size_t)(N+1)*4);
  size_t oCU  = alloc((size_t)N*4);
  size_t zbytes = (size_t)N*4 + (size_t)N2*4 + (size_t)N*4 + (size_t)G*128*4;
  size_t oZ   = alloc(zbytes);               // cnt_row0 | cnt_row1 | cnt_col | genc
  size_t oCR0 = oZ;
  size_t oCR1 = oCR0 + (size_t)N*4;
  size_t oCC  = oCR1 + (size_t)N2*4;
  size_t oGE  = oCC  + (size_t)N*4;
  size_t oD0  = alloc((size_t)N*4);
  size_t oD1  = alloc((size_t)N2*4);
  size_t oWsp = alloc((size_t)(16384*2 + 16384*2 + 32768*2 + 32768*2)*2);

  float* regA   = (float*)(ws + oA);
  float* regB   = (float*)(ws + oB);
  float* xp     = regB;                                  // 25000x128 (h0 dead by then)
  float* h1m    = (float*)(ws + oB + (size_t)N2*128*4);  // 25000x128
  float* w0     = (float*)(ws + oW0);
  float* w1     = (float*)(ws + oW1);
  int*   rs     = (int*)(ws + oRS);
  float* c0s    = (float*)(ws + oC0);
  float* c1s    = (float*)(ws + oC1);
  int*   starts = (int*)(ws + oST);
  int*   cursor = (int*)(ws + oCU);
  int*   cr0    = (int*)(ws + oCR0);
  int*   cr1    = (int*)(ws + oCR1);
  int*   cc     = (int*)(ws + oCC);
  unsigned* genc= (unsigned*)(ws + oGE);
  float* dis0   = (float*)(ws + oD0);
  float* dis1   = (float*)(ws + oD1);
  short* l0W1h  = (short*)(ws + oWsp);
  short* l0W1l  = l0W1h + 16384;
  short* l0W2h  = l0W1l + 16384;
  short* l0W2l  = l0W2h + 16384;
  short* l1W1h  = l0W2l + 16384;
  short* l1W1l  = l1W1h + 32768;
  short* l1W2h  = l1W1l + 32768;
  short* l1W2l  = l1W2h + 32768;

  hipMemsetAsync(ws + oZ, 0, zbytes, stream);

  prep_w_kernel<<<64, 256, 0, stream>>>(l0_W1, l0W1h, l0W1l, 128, 128);
  prep_w_kernel<<<64, 256, 0, stream>>>(l0_W2, l0W2h, l0W2l, 128, 128);
  prep_w_kernel<<<128, 256, 0, stream>>>(l1_W1, l1W1h, l1W1l, 128, 256);
  prep_w_kernel<<<128, 256, 0, stream>>>(l1_W2, l1W2h, l1W2l, 256, 128);

  edge_pass_kernel<<<(E+255)/256, 256, 0, stream>>>(ei, ea, l0_We, l0_be, l1_We, l1_be,
                                                    w0, w1, cr0, cr1, cc, E);
  dis_kernel<<<(N+255)/256, 256, 0, stream>>>(cr0, dis0, N);
  dis_kernel<<<(N2+255)/256, 256, 0, stream>>>(cr1, dis1, N2);
  scan_kernel<<<1, 1024, 0, stream>>>(cc, starts, cursor, N);
  fill_kernel<<<(E+255)/256, 256, 0, stream>>>(ei, w0, w1, dis0, dis1, cursor, rs, c0s, c1s, E);

  // MLP0: x -> hmid0(regA) -> h0(regB)
  gemm_split<8><<<(N+63)/64, 256, 0, stream>>>(x, l0W1h, l0W1l, l0_b1, l0_s, l0_t, regA, N, 128, 1);
  gemm_split<8><<<(N+63)/64, 256, 0, stream>>>(regA, l0W2h, l0W2l, l0_b2, nullptr, nullptr, regB, N, 128, 0);
  // aggregate layer0 -> hL0 (regA)
  mp0_kernel<<<(N+3)/4, 256, 0, stream>>>(starts, rs, c0s, dis0, regB, origin, l0_We, l0_be, regA, N);
  // pair pool -> xp (regB low half)
  pool_kernel<<<(N2*32+255)/256, 256, 0, stream>>>(regA, xp, N2*32);
  // MLP1: xp -> hmid1(regA, 25000x256) -> h1m(regB high half)
  gemm_split<16><<<(N2+63)/64, 256, 0, stream>>>(xp, l1W1h, l1W1l, l1_b1, l1_s, l1_t, regA, N2, 128, 1);
  gemm_split<8><<<(N2+63)/64, 256, 0, stream>>>(regA, l1W2h, l1W2l, l1_b2, nullptr, nullptr, h1m, N2, 256, 0);
  // aggregate layer1 + global max pool
  mp1_kernel<<<(N2+3)/4, 256, 0, stream>>>(starts, rs, c1s, dis1, h1m, l1_We, l1_be, batchp, genc, N2);
  // head
  head_kernel<<<1, 256, 0, stream>>>(genc, hd_W1, hd_b1, hd_s, hd_t, hd_W2, hd_b2, (float*)d_out);
}

// Round 2
// 500.784 us; speedup vs baseline: 1.1133x; 1.1133x over previous
//
#include <hip/hip_runtime.h>

typedef __attribute__((ext_vector_type(4))) float f32x4;
typedef __attribute__((ext_vector_type(8))) short bf16x8;

__device__ __forceinline__ unsigned short f32_to_bf16_rne(float f){
  unsigned u = __builtin_bit_cast(unsigned, f);
  unsigned r = u + 0x7FFFu + ((u >> 16) & 1u);
  return (unsigned short)(r >> 16);
}
__device__ __forceinline__ float bf16_hi_to_f32(unsigned short h){
  unsigned u = ((unsigned)h) << 16;
  return __builtin_bit_cast(float, u);
}
__device__ __forceinline__ float leakyf(float v){ return v > 0.f ? v : 0.01f*v; }
__device__ __forceinline__ unsigned f32_ord(float f){
  unsigned u = __builtin_bit_cast(unsigned, f);
  return (u & 0x80000000u) ? ~u : (u | 0x80000000u);
}

// ---------------- weight pre-split into MFMA B-fragment layout (hi/lo bf16) -------------
__global__ void prep_w_kernel(const float* __restrict__ W, short* __restrict__ Wh,
                              short* __restrict__ Wl, int K, int N)
{
  int total = K*N;
  int NF = N >> 4;
  for (int i = blockIdx.x*blockDim.x + threadIdx.x; i < total; i += gridDim.x*blockDim.x){
    int k = i / N, n = i % N;
    float w = W[i];
    unsigned short h = f32_to_bf16_rne(w);
    unsigned short l = f32_to_bf16_rne(w - bf16_hi_to_f32(h));
    int kb = k >> 5, kr = k & 31, cb = n >> 4;
    int lanei = ((kr >> 3) << 4) | (n & 15);
    size_t dst = (((size_t)(kb*NF + cb))*64 + lanei)*8 + (kr & 7);
    Wh[dst] = (short)h; Wl[dst] = (short)l;
  }
}

// ---------------- edge pass: histograms + per-edge edge-weights -------------------------
__global__ void edge_pass_kernel(const int* __restrict__ ei, const float* __restrict__ ea,
                                 const float* __restrict__ We0, const float* __restrict__ be0,
                                 const float* __restrict__ We1, const float* __restrict__ be1,
                                 float* __restrict__ w0, float* __restrict__ w1,
                                 int* __restrict__ cnt_row0, int* __restrict__ cnt_row1,
                                 int* __restrict__ cnt_col, int E)
{
  float A0[12], A1[12];
#pragma unroll
  for (int i=0;i<12;i++){ A0[i]=We0[i]; A1[i]=We1[i]; }
  float b0 = be0[0], b1 = be1[0];
  for (int e = blockIdx.x*blockDim.x + threadIdx.x; e < E; e += gridDim.x*blockDim.x){
    int r = ei[e], c = ei[E+e];
    atomicAdd(&cnt_row0[r], 1);
    atomicAdd(&cnt_col[c], 1);
    if ((r>>1) != (c>>1)) atomicAdd(&cnt_row1[r>>1], 1);
    const float* ap = ea + (size_t)e*12;
    float s0 = b0, s1 = b1;
#pragma unroll
    for (int i=0;i<12;i++){ float v = ap[i]; s0 += v*A0[i]; s1 += v*A1[i]; }
    w0[e] = s0; w1[e] = s1;
  }
}

__global__ void dis_kernel(const int* __restrict__ cnt, float* __restrict__ dis, int n)
{
  for (int i = blockIdx.x*blockDim.x + threadIdx.x; i < n; i += gridDim.x*blockDim.x)
    dis[i] = rsqrtf((float)cnt[i] + 1.0f);
}

// ---------------- 3-pass parallel exclusive scan over cnt_col ---------------------------
__global__ void scan_partial_kernel(const int* __restrict__ cnt, int* __restrict__ bsum, int N)
{
  __shared__ int ws[4];
  int t = threadIdx.x, lane = t & 63, wv = t >> 6;
  int i = blockIdx.x*256 + t;
  int v = (i < N) ? cnt[i] : 0;
#pragma unroll
  for (int d = 1; d < 64; d <<= 1) v += __shfl_xor(v, d);
  if (lane == 0) ws[wv] = v;
  __syncthreads();
  if (t == 0) bsum[blockIdx.x] = ws[0]+ws[1]+ws[2]+ws[3];
}

__global__ void scan_bsums_kernel(int* __restrict__ bsum, int NB)
{
  int lane = threadIdx.x;  // 64 threads, 1 wave
  int carry = 0;
  for (int base = 0; base < NB; base += 64){
    int i = base + lane;
    int v = (i < NB) ? bsum[i] : 0;
    int x = v;
#pragma unroll
    for (int d = 1; d < 64; d <<= 1){
      int y = __shfl_up(x, d);
      if (lane >= d) x += y;
    }
    if (i < NB) bsum[i] = x - v + carry;   // exclusive
    carry += __shfl(x, 63);
  }
}

__global__ void scan_final_kernel(const int* __restrict__ cnt, const int* __restrict__ bsum,
                                  int* __restrict__ starts, int* __restrict__ cursor, int N)
{
  __shared__ int wsum[4];
  int t = threadIdx.x, lane = t & 63, wv = t >> 6;
  int i = blockIdx.x*256 + t;
  int v = (i < N) ? cnt[i] : 0;
  int x = v;
#pragma unroll
  for (int d = 1; d < 64; d <<= 1){
    int y = __shfl_up(x, d);
    if (lane >= d) x += y;
  }
  if (lane == 63) wsum[wv] = x;
  __syncthreads();
  int woff = 0;
#pragma unroll
  for (int j = 0; j < 4; j++) if (j < wv) woff += wsum[j];
  int base = bsum[blockIdx.x] + woff;
  if (i < N){
    starts[i+1] = base + x;
    cursor[i]   = base + x - v;
  }
  if (blockIdx.x == 0 && t == 0) starts[0] = 0;
}

// ---------------- CSR fill with packed payload ------------------------------------------
__global__ void fill_kernel(const int* __restrict__ ei, const float* __restrict__ w0,
                            const float* __restrict__ w1, const float* __restrict__ dis0,
                            const float* __restrict__ dis1, int* __restrict__ cursor,
                            int* __restrict__ rs, float* __restrict__ c0s,
                            float* __restrict__ c1s, int E)
{
  for (int e = blockIdx.x*blockDim.x + threadIdx.x; e < E; e += gridDim.x*blockDim.x){
    int r = ei[e], c = ei[E+e];
    int pos = atomicAdd(&cursor[c], 1);
    rs[pos]  = r;
    c0s[pos] = dis0[r] * w0[e];
    c1s[pos] = dis1[r>>1] * w1[e];
  }
}

// ---------------- split-bf16 MFMA GEMM: Y = epilogue(X @ W + b) -------------------------
// flags&1: y = leaky(y*scale + shift);  flags&2: store bf16 (ushort) else f32
template<int NF>
__global__ __launch_bounds__(256) void gemm_split(
    const float* __restrict__ X, const short* __restrict__ Wh, const short* __restrict__ Wl,
    const float* __restrict__ bias, const float* __restrict__ scale, const float* __restrict__ shift,
    void* __restrict__ Yv, int M, int K, int flags)
{
  const int Nn = NF*16;
  int w = threadIdx.x >> 6, lane = threadIdx.x & 63;
  int r0 = blockIdx.x*64 + w*16;
  int arow = r0 + (lane & 15);
  long arow_c = (arow < M) ? arow : (M-1);
  int kHi = (lane >> 4) << 3;
  f32x4 acc[NF];
#pragma unroll
  for (int i=0;i<NF;i++){
#pragma unroll
    for (int j=0;j<4;j++) acc[i][j] = 0.f;
  }
  int KB = K >> 5;
  const float* aprow = X + arow_c*(long)K + kHi;
  for (int kb=0; kb<KB; ++kb){
    const float* ap = aprow + kb*32;
    f32x4 a0 = *(const f32x4*)ap;
    f32x4 a1 = *(const f32x4*)(ap+4);
    bf16x8 ah, al;
#pragma unroll
    for (int j=0;j<8;j++){
      float f = (j<4) ? a0[j] : a1[j-4];
      unsigned short h = f32_to_bf16_rne(f);
      ah[j] = (short)h;
      al[j] = (short)f32_to_bf16_rne(f - bf16_hi_to_f32(h));
    }
    const short* bp  = Wh + ((size_t)kb*NF*64 + lane)*8;
    const short* bpl = Wl + ((size_t)kb*NF*64 + lane)*8;
#pragma unroll
    for (int cb=0; cb<NF; ++cb){
      bf16x8 bh = *(const bf16x8*)(bp  + (size_t)cb*512);
      bf16x8 bl = *(const bf16x8*)(bpl + (size_t)cb*512);
      acc[cb] = __builtin_amdgcn_mfma_f32_16x16x32_bf16(ah, bh, acc[cb], 0,0,0);
      acc[cb] = __builtin_amdgcn_mfma_f32_16x16x32_bf16(al, bh, acc[cb], 0,0,0);
      acc[cb] = __builtin_amdgcn_mfma_f32_16x16x32_bf16(ah, bl, acc[cb], 0,0,0);
    }
  }
  int crow = r0 + ((lane >> 4) << 2);
  int ccol = lane & 15;
  float* Yf = (float*)Yv;
  unsigned short* Yb = (unsigned short*)Yv;
#pragma unroll
  for (int cb=0; cb<NF; ++cb){
    int c = cb*16 + ccol;
    float b = bias[c];
    float sc = 1.f, sh = 0.f;
    if (flags & 1){ sc = scale[c]; sh = shift[c]; }
#pragma unroll
    for (int r=0;r<4;r++){
      int row = crow + r;
      if (row < M){
        float v = acc[cb][r] + b;
        if (flags & 1){ v = v*sc + sh; v = leakyf(v); }
        if (flags & 2) Yb[(size_t)row*Nn + c] = f32_to_bf16_rne(v);
        else           Yf[(size_t)row*Nn + c] = v;
      }
    }
  }
}

// ---------------- layer-0 aggregate: one wave per node, bf16 gather table ---------------
__global__ __launch_bounds__(256) void mp0_kernel(
    const int* __restrict__ starts, const int* __restrict__ rs, const float* __restrict__ c0s,
    const float* __restrict__ dis0, const unsigned* __restrict__ h0b, const float* __restrict__ origin,
    const float* __restrict__ We, const float* __restrict__ be, float* __restrict__ out, int N)
{
  int n = blockIdx.x*4 + (threadIdx.x >> 6);
  if (n >= N) return;
  int lane = threadIdx.x & 63;
  float wself = be[0];
#pragma unroll
  for (int i=0;i<12;i++) wself += We[i];
  int s = starts[n], e = starts[n+1];
  float dn = dis0[n];
  float ax = 0.f, ay = 0.f;
  for (int idx = s; idx < e; ++idx){
    int r = rs[idx];
    float cf = c0s[idx];
    unsigned u = h0b[(size_t)r*64 + lane];
    ax += cf * bf16_hi_to_f32((unsigned short)(u & 0xFFFF));
    ay += cf * bf16_hi_to_f32((unsigned short)(u >> 16));
  }
  float cs = dn*dn*wself;
  unsigned us = h0b[(size_t)n*64 + lane];
  const float2 og = *(const float2*)(origin + (size_t)n*128 + lane*2);
  float ox = leakyf(dn*ax + cs*bf16_hi_to_f32((unsigned short)(us & 0xFFFF)) + og.x);
  float oy = leakyf(dn*ay + cs*bf16_hi_to_f32((unsigned short)(us >> 16)) + og.y);
  float2 o2 = {ox, oy};
  *(float2*)(out + (size_t)n*128 + lane*2) = o2;
}

// ---------------- pair pool: xp[j] = max(h[2j], h[2j+1]) -------------------------------
__global__ void pool_kernel(const float* __restrict__ h, float* __restrict__ xp, int n4)
{
  for (int i = blockIdx.x*blockDim.x + threadIdx.x; i < n4; i += gridDim.x*blockDim.x){
    int j = i >> 5, c4 = i & 31;
    const f32x4 a = *(const f32x4*)(h + ((size_t)(2*j))*128 + c4*4);
    const f32x4 b = *(const f32x4*)(h + ((size_t)(2*j+1))*128 + c4*4);
    f32x4 m;
#pragma unroll
    for (int q=0;q<4;q++) m[q] = fmaxf(a[q], b[q]);
    *(f32x4*)(xp + (size_t)j*128 + c4*4) = m;
  }
}

// ---------------- layer-1 aggregate + global max pool, bf16 gather table ----------------
__global__ __launch_bounds__(256) void mp1_kernel(
    const int* __restrict__ starts, const int* __restrict__ rs, const float* __restrict__ c1s,
    const float* __restrict__ dis1, const unsigned* __restrict__ h1b,
    const float* __restrict__ We, const float* __restrict__ be,
    const int* __restrict__ batch_p, unsigned* __restrict__ genc, int N2)
{
  int n = blockIdx.x*4 + (threadIdx.x >> 6);
  if (n >= N2) return;
  int lane = threadIdx.x & 63;
  float wself = be[0];
#pragma unroll
  for (int i=0;i<12;i++) wself += We[i];
  int s = starts[2*n], e = starts[2*n+2];
  float dn = dis1[n];
  float ax = 0.f, ay = 0.f;
  for (int idx = s; idx < e; ++idx){
    int r = rs[idx];
    int rp = r >> 1;
    if (rp == n) continue;
    float cf = c1s[idx];
    unsigned u = h1b[(size_t)rp*64 + lane];
    ax += cf * bf16_hi_to_f32((unsigned short)(u & 0xFFFF));
    ay += cf * bf16_hi_to_f32((unsigned short)(u >> 16));
  }
  float cs = dn*dn*wself;
  unsigned us = h1b[(size_t)n*64 + lane];
  float ox = leakyf(dn*ax + cs*bf16_hi_to_f32((unsigned short)(us & 0xFFFF)));
  float oy = leakyf(dn*ay + cs*bf16_hi_to_f32((unsigned short)(us >> 16)));
  int b = batch_p[n];
  atomicMax(&genc[(size_t)b*128 + lane*2    ], f32_ord(ox));
  atomicMax(&genc[(size_t)b*128 + lane*2 + 1], f32_ord(oy));
}

// ---------------- head MLP: [64,128] -> [64,64] -> [64] --------------------------------
__global__ __launch_bounds__(256) void head_kernel(
    const unsigned* __restrict__ genc, const float* __restrict__ W1, const float* __restrict__ b1,
    const float* __restrict__ s, const float* __restrict__ t,
    const float* __restrict__ W2, const float* __restrict__ b2, float* __restrict__ out)
{
  __shared__ float g[64][128];
  __shared__ float hh[64][64];
  int tid = threadIdx.x;
  for (int i = tid; i < 64*128; i += 256){
    unsigned u = genc[i];
    unsigned bits = (u & 0x80000000u) ? (u & 0x7FFFFFFFu) : ~u;
    g[i>>7][i&127] = __builtin_bit_cast(float, bits);
  }
  __syncthreads();
  int c = tid & 63;
  int q0 = tid >> 6;
  float accv[16];
#pragma unroll
  for (int i=0;i<16;i++) accv[i] = 0.f;
  for (int k=0;k<128;k++){
    float wv = W1[k*64 + c];
#pragma unroll
    for (int i=0;i<16;i++) accv[i] += g[q0*16+i][k] * wv;
  }
  float sc = s[c], sh = t[c], bb = b1[c];
#pragma unroll
  for (int i=0;i<16;i++){
    float v = (accv[i] + bb)*sc + sh;
    hh[q0*16+i][c] = leakyf(v);
  }
  __syncthreads();
  if (tid < 64){
    float a = b2[0];
    for (int k=0;k<64;k++) a += hh[tid][k]*W2[k];
    out[tid] = a;
  }
}

extern "C" void kernel_launch(void* const* d_in, const int* in_sizes, int n_in,
                              void* d_out, int out_size, void* d_ws, size_t ws_size,
                              hipStream_t stream)
{
  const float* x      = (const float*)d_in[0];
  const float* origin = (const float*)d_in[1];
  const float* ea     = (const float*)d_in[2];
  const int*   ei     = (const int*)d_in[3];
  const int*   batchp = (const int*)d_in[5];
  const float* l0_W1 = (const float*)d_in[6];
  const float* l0_b1 = (const float*)d_in[7];
  const float* l0_s  = (const float*)d_in[8];
  const float* l0_t  = (const float*)d_in[9];
  const float* l0_W2 = (const float*)d_in[10];
  const float* l0_b2 = (const float*)d_in[11];
  const float* l0_We = (const float*)d_in[12];
  const float* l0_be = (const float*)d_in[13];
  const float* l1_W1 = (const float*)d_in[14];
  const float* l1_b1 = (const float*)d_in[15];
  const float* l1_s  = (const float*)d_in[16];
  const float* l1_t  = (const float*)d_in[17];
  const float* l1_W2 = (const float*)d_in[18];
  const float* l1_b2 = (const float*)d_in[19];
  const float* l1_We = (const float*)d_in[20];
  const float* l1_be = (const float*)d_in[21];
  const float* hd_W1 = (const float*)d_in[22];
  const float* hd_b1 = (const float*)d_in[23];
  const float* hd_s  = (const float*)d_in[24];
  const float* hd_t  = (const float*)d_in[25];
  const float* hd_W2 = (const float*)d_in[26];
  const float* hd_b2 = (const float*)d_in[27];

  const int N  = in_sizes[0] / 128;   // 50000
  const int E  = in_sizes[2] / 12;    // 800000
  const int N2 = in_sizes[5];         // 25000
  const int G  = out_size;            // 64
  const int NB = (N + 255) / 256;     // scan blocks

  char* ws = (char*)d_ws;
  size_t off = 0;
  auto alloc = [&](size_t b){ size_t o = off; off += (b + 255) & ~(size_t)255; return o; };
  size_t oA   = alloc((size_t)N*128*4);      // hmid0 / hL0 / hmid1(25000x256)
  size_t oB   = alloc((size_t)N*128*4);      // [0,12.8M): h0b bf16 -> h1b bf16 ; [12.8M,25.6M): xp f32
  size_t oW0  = alloc((size_t)E*4);
  size_t oW1  = alloc((size_t)E*4);
  size_t oRS  = alloc((size_t)E*4);
  size_t oC0  = alloc((size_t)E*4);
  size_t oC1  = alloc((size_t)E*4);
  size_t oST  = alloc((size_t)(N+1)*4);
  size_t oCU  = alloc((size_t)N*4);
  size_t oBS  = alloc((size_t)NB*4);
  size_t zbytes = (size_t)N*4 + (size_t)N2*4 + (size_t)N*4 + (size_t)G*128*4;
  size_t oZ   = alloc(zbytes);               // cnt_row0 | cnt_row1 | cnt_col | genc
  size_t oCR0 = oZ;
  size_t oCR1 = oCR0 + (size_t)N*4;
  size_t oCC  = oCR1 + (size_t)N2*4;
  size_t oGE  = oCC  + (size_t)N*4;
  size_t oD0  = alloc((size_t)N*4);
  size_t oD1  = alloc((size_t)N2*4);
  size_t oWsp = alloc((size_t)(16384*2 + 16384*2 + 32768*2 + 32768*2)*2);

  float* regA   = (float*)(ws + oA);
  unsigned* h0b = (unsigned*)(ws + oB);                  // 50000x128 bf16 (as uints)
  unsigned* h1b = (unsigned*)(ws + oB);                  // 25000x128 bf16 (h0b dead)
  float* xp     = (float*)(ws + oB + (size_t)N2*128*4);  // 25000x128 f32
  float* w0     = (float*)(ws + oW0);
  float* w1     = (float*)(ws + oW1);
  int*   rs     = (int*)(ws + oRS);
  float* c0s    = (float*)(ws + oC0);
  float* c1s    = (float*)(ws + oC1);
  int*   starts = (int*)(ws + oST);
  int*   cursor = (int*)(ws + oCU);
  int*   bsum   = (int*)(ws + oBS);
  int*   cr0    = (int*)(ws + oCR0);
  int*   cr1    = (int*)(ws + oCR1);
  int*   cc     = (int*)(ws + oCC);
  unsigned* genc= (unsigned*)(ws + oGE);
  float* dis0   = (float*)(ws + oD0);
  float* dis1   = (float*)(ws + oD1);
  short* l0W1h  = (short*)(ws + oWsp);
  short* l0W1l  = l0W1h + 16384;
  short* l0W2h  = l0W1l + 16384;
  short* l0W2l  = l0W2h + 16384;
  short* l1W1h  = l0W2l + 16384;
  short* l1W1l  = l1W1h + 32768;
  short* l1W2h  = l1W1l + 32768;
  short* l1W2l  = l1W2h + 32768;

  hipMemsetAsync(ws + oZ, 0, zbytes, stream);

  prep_w_kernel<<<64, 256, 0, stream>>>(l0_W1, l0W1h, l0W1l, 128, 128);
  prep_w_kernel<<<64, 256, 0, stream>>>(l0_W2, l0W2h, l0W2l, 128, 128);
  prep_w_kernel<<<128, 256, 0, stream>>>(l1_W1, l1W1h, l1W1l, 128, 256);
  prep_w_kernel<<<128, 256, 0, stream>>>(l1_W2, l1W2h, l1W2l, 256, 128);

  edge_pass_kernel<<<(E+255)/256, 256, 0, stream>>>(ei, ea, l0_We, l0_be, l1_We, l1_be,
                                                    w0, w1, cr0, cr1, cc, E);
  dis_kernel<<<(N+255)/256, 256, 0, stream>>>(cr0, dis0, N);
  dis_kernel<<<(N2+255)/256, 256, 0, stream>>>(cr1, dis1, N2);
  scan_partial_kernel<<<NB, 256, 0, stream>>>(cc, bsum, N);
  scan_bsums_kernel<<<1, 64, 0, stream>>>(bsum, NB);
  scan_final_kernel<<<NB, 256, 0, stream>>>(cc, bsum, starts, cursor, N);
  fill_kernel<<<(E+255)/256, 256, 0, stream>>>(ei, w0, w1, dis0, dis1, cursor, rs, c0s, c1s, E);

  // MLP0: x -> hmid0(regA) -> h0b (bf16)
  gemm_split<8><<<(N+63)/64, 256, 0, stream>>>(x, l0W1h, l0W1l, l0_b1, l0_s, l0_t, regA, N, 128, 1);
  gemm_split<8><<<(N+63)/64, 256, 0, stream>>>(regA, l0W2h, l0W2l, l0_b2, nullptr, nullptr, h0b, N, 128, 2);
  // aggregate layer0 -> hL0 (regA)
  mp0_kernel<<<(N+3)/4, 256, 0, stream>>>(starts, rs, c0s, dis0, h0b, origin, l0_We, l0_be, regA, N);
  // pair pool -> xp
  pool_kernel<<<(N2*32+255)/256, 256, 0, stream>>>(regA, xp, N2*32);
  // MLP1: xp -> hmid1(regA, 25000x256) -> h1b (bf16)
  gemm_split<16><<<(N2+63)/64, 256, 0, stream>>>(xp, l1W1h, l1W1l, l1_b1, l1_s, l1_t, regA, N2, 128, 1);
  gemm_split<8><<<(N2+63)/64, 256, 0, stream>>>(regA, l1W2h, l1W2l, l1_b2, nullptr, nullptr, h1b, N2, 256, 2);
  // aggregate layer1 + global max pool
  mp1_kernel<<<(N2+3)/4, 256, 0, stream>>>(starts, rs, c1s, dis1, h1b, l1_We, l1_be, batchp, genc, N2);
  // head
  head_kernel<<<1, 256, 0, stream>>>(genc, hd_W1, hd_b1, hd_s, hd_t, hd_W2, hd_b2, (float*)d_out);
}

// Round 3
// 410.404 us; speedup vs baseline: 1.3584x; 1.2202x over previous
//
#include <hip/hip_runtime.h>

typedef __attribute__((ext_vector_type(4))) float f32x4;
typedef __attribute__((ext_vector_type(8))) short bf16x8;

__device__ __forceinline__ unsigned short f32_to_bf16_rne(float f){
  unsigned u = __builtin_bit_cast(unsigned, f);
  unsigned r = u + 0x7FFFu + ((u >> 16) & 1u);
  return (unsigned short)(r >> 16);
}
__device__ __forceinline__ float bf16_hi_to_f32(unsigned short h){
  unsigned u = ((unsigned)h) << 16;
  return __builtin_bit_cast(float, u);
}
__device__ __forceinline__ float blo(unsigned u){ return bf16_hi_to_f32((unsigned short)(u & 0xFFFF)); }
__device__ __forceinline__ float bhi(unsigned u){ return bf16_hi_to_f32((unsigned short)(u >> 16)); }
__device__ __forceinline__ float leakyf(float v){ return v > 0.f ? v : 0.01f*v; }
__device__ __forceinline__ unsigned f32_ord(float f){
  unsigned u = __builtin_bit_cast(unsigned, f);
  return (u & 0x80000000u) ? ~u : (u | 0x80000000u);
}

// ---------------- weight pre-split into MFMA B-fragment layout (hi/lo bf16) -------------
__global__ void prep_w_kernel(const float* __restrict__ W, short* __restrict__ Wh,
                              short* __restrict__ Wl, int K, int N)
{
  int total = K*N;
  int NF = N >> 4;
  for (int i = blockIdx.x*blockDim.x + threadIdx.x; i < total; i += gridDim.x*blockDim.x){
    int k = i / N, n = i % N;
    float w = W[i];
    unsigned short h = f32_to_bf16_rne(w);
    unsigned short l = f32_to_bf16_rne(w - bf16_hi_to_f32(h));
    int kb = k >> 5, kr = k & 31, cb = n >> 4;
    int lanei = ((kr >> 3) << 4) | (n & 15);
    size_t dst = (((size_t)(kb*NF + cb))*64 + lanei)*8 + (kr & 7);
    Wh[dst] = (short)h; Wl[dst] = (short)l;
  }
}

// ---------------- edge pass: histograms + per-edge edge-weights -------------------------
__global__ void edge_pass_kernel(const int* __restrict__ ei, const float* __restrict__ ea,
                                 const float* __restrict__ We0, const float* __restrict__ be0,
                                 const float* __restrict__ We1, const float* __restrict__ be1,
                                 float* __restrict__ w0, float* __restrict__ w1,
                                 int* __restrict__ cnt_row0, int* __restrict__ cnt_row1,
                                 int* __restrict__ cnt_col, int E)
{
  float A0[12], A1[12];
#pragma unroll
  for (int i=0;i<12;i++){ A0[i]=We0[i]; A1[i]=We1[i]; }
  float b0 = be0[0], b1 = be1[0];
  for (int e = blockIdx.x*blockDim.x + threadIdx.x; e < E; e += gridDim.x*blockDim.x){
    int r = ei[e], c = ei[E+e];
    atomicAdd(&cnt_row0[r], 1);
    atomicAdd(&cnt_col[c], 1);
    if ((r>>1) != (c>>1)) atomicAdd(&cnt_row1[r>>1], 1);
    const float* ap = ea + (size_t)e*12;
    float s0 = b0, s1 = b1;
#pragma unroll
    for (int i=0;i<12;i++){ float v = ap[i]; s0 += v*A0[i]; s1 += v*A1[i]; }
    w0[e] = s0; w1[e] = s1;
  }
}

__global__ void dis_kernel(const int* __restrict__ cnt, float* __restrict__ dis, int n)
{
  for (int i = blockIdx.x*blockDim.x + threadIdx.x; i < n; i += gridDim.x*blockDim.x)
    dis[i] = rsqrtf((float)cnt[i] + 1.0f);
}

// ---------------- 3-pass parallel exclusive scan over cnt_col ---------------------------
__global__ void scan_partial_kernel(const int* __restrict__ cnt, int* __restrict__ bsum, int N)
{
  __shared__ int ws[4];
  int t = threadIdx.x, lane = t & 63, wv = t >> 6;
  int i = blockIdx.x*256 + t;
  int v = (i < N) ? cnt[i] : 0;
#pragma unroll
  for (int d = 1; d < 64; d <<= 1) v += __shfl_xor(v, d);
  if (lane == 0) ws[wv] = v;
  __syncthreads();
  if (t == 0) bsum[blockIdx.x] = ws[0]+ws[1]+ws[2]+ws[3];
}

__global__ void scan_bsums_kernel(int* __restrict__ bsum, int NB)
{
  int lane = threadIdx.x;  // 64 threads, 1 wave
  int carry = 0;
  for (int base = 0; base < NB; base += 64){
    int i = base + lane;
    int v = (i < NB) ? bsum[i] : 0;
    int x = v;
#pragma unroll
    for (int d = 1; d < 64; d <<= 1){
      int y = __shfl_up(x, d);
      if (lane >= d) x += y;
    }
    if (i < NB) bsum[i] = x - v + carry;   // exclusive
    carry += __shfl(x, 63);
  }
}

__global__ void scan_final_kernel(const int* __restrict__ cnt, const int* __restrict__ bsum,
                                  int* __restrict__ starts, int* __restrict__ cursor, int N)
{
  __shared__ int wsum[4];
  int t = threadIdx.x, lane = t & 63, wv = t >> 6;
  int i = blockIdx.x*256 + t;
  int v = (i < N) ? cnt[i] : 0;
  int x = v;
#pragma unroll
  for (int d = 1; d < 64; d <<= 1){
    int y = __shfl_up(x, d);
    if (lane >= d) x += y;
  }
  if (lane == 63) wsum[wv] = x;
  __syncthreads();
  int woff = 0;
#pragma unroll
  for (int j = 0; j < 4; j++) if (j < wv) woff += wsum[j];
  int base = bsum[blockIdx.x] + woff;
  if (i < N){
    starts[i+1] = base + x;
    cursor[i]   = base + x - v;
  }
  if (blockIdx.x == 0 && t == 0) starts[0] = 0;
}

// ---------------- CSR fill with packed payload ------------------------------------------
__global__ void fill_kernel(const int* __restrict__ ei, const float* __restrict__ w0,
                            const float* __restrict__ w1, const float* __restrict__ dis0,
                            const float* __restrict__ dis1, int* __restrict__ cursor,
                            int* __restrict__ rs, float* __restrict__ c0s,
                            float* __restrict__ c1s, int E)
{
  for (int e = blockIdx.x*blockDim.x + threadIdx.x; e < E; e += gridDim.x*blockDim.x){
    int r = ei[e], c = ei[E+e];
    int pos = atomicAdd(&cursor[c], 1);
    rs[pos]  = r;
    c0s[pos] = dis0[r] * w0[e];
    c1s[pos] = dis1[r>>1] * w1[e];
  }
}

// ---------------- split-bf16 MFMA GEMM: Y = epilogue(X @ W + b) -------------------------
// flags&1: y = leaky(y*scale + shift);  flags&2: store bf16 (ushort) else f32
template<int NF>
__global__ __launch_bounds__(256) void gemm_split(
    const float* __restrict__ X, const short* __restrict__ Wh, const short* __restrict__ Wl,
    const float* __restrict__ bias, const float* __restrict__ scale, const float* __restrict__ shift,
    void* __restrict__ Yv, int M, int K, int flags)
{
  const int Nn = NF*16;
  int w = threadIdx.x >> 6, lane = threadIdx.x & 63;
  int r0 = blockIdx.x*64 + w*16;
  int arow = r0 + (lane & 15);
  long arow_c = (arow < M) ? arow : (M-1);
  int kHi = (lane >> 4) << 3;
  f32x4 acc[NF];
#pragma unroll
  for (int i=0;i<NF;i++){
#pragma unroll
    for (int j=0;j<4;j++) acc[i][j] = 0.f;
  }
  int KB = K >> 5;
  const float* aprow = X + arow_c*(long)K + kHi;
  for (int kb=0; kb<KB; ++kb){
    const float* ap = aprow + kb*32;
    f32x4 a0 = *(const f32x4*)ap;
    f32x4 a1 = *(const f32x4*)(ap+4);
    bf16x8 ah, al;
#pragma unroll
    for (int j=0;j<8;j++){
      float f = (j<4) ? a0[j] : a1[j-4];
      unsigned short h = f32_to_bf16_rne(f);
      ah[j] = (short)h;
      al[j] = (short)f32_to_bf16_rne(f - bf16_hi_to_f32(h));
    }
    const short* bp  = Wh + ((size_t)kb*NF*64 + lane)*8;
    const short* bpl = Wl + ((size_t)kb*NF*64 + lane)*8;
#pragma unroll
    for (int cb=0; cb<NF; ++cb){
      bf16x8 bh = *(const bf16x8*)(bp  + (size_t)cb*512);
      bf16x8 bl = *(const bf16x8*)(bpl + (size_t)cb*512);
      acc[cb] = __builtin_amdgcn_mfma_f32_16x16x32_bf16(ah, bh, acc[cb], 0,0,0);
      acc[cb] = __builtin_amdgcn_mfma_f32_16x16x32_bf16(al, bh, acc[cb], 0,0,0);
      acc[cb] = __builtin_amdgcn_mfma_f32_16x16x32_bf16(ah, bl, acc[cb], 0,0,0);
    }
  }
  int crow = r0 + ((lane >> 4) << 2);
  int ccol = lane & 15;
  float* Yf = (float*)Yv;
  unsigned short* Yb = (unsigned short*)Yv;
#pragma unroll
  for (int cb=0; cb<NF; ++cb){
    int c = cb*16 + ccol;
    float b = bias[c];
    float sc = 1.f, sh = 0.f;
    if (flags & 1){ sc = scale[c]; sh = shift[c]; }
#pragma unroll
    for (int r=0;r<4;r++){
      int row = crow + r;
      if (row < M){
        float v = acc[cb][r] + b;
        if (flags & 1){ v = v*sc + sh; v = leakyf(v); }
        if (flags & 2) Yb[(size_t)row*Nn + c] = f32_to_bf16_rne(v);
        else           Yf[(size_t)row*Nn + c] = v;
      }
    }
  }
}

// ---- unrolled gather-accumulate over CSR slot range [s,e): 8 outstanding gathers -------
// SKIPSELF: zero coefficient when (rs>>1)==selfp
template<bool SKIPSELF>
__device__ __forceinline__ void gather_range(const int* __restrict__ rs,
                                             const float* __restrict__ cs,
                                             const unsigned* __restrict__ tab, int lane,
                                             int s, int e, int shift, int selfp,
                                             float& ax, float& ay)
{
  int idx = s;
  for (; idx + 8 <= e; idx += 8){
    int r[8]; float cf[8]; unsigned u[8];
#pragma unroll
    for (int j=0;j<8;j++){ r[j] = rs[idx+j] >> shift; cf[j] = cs[idx+j]; }
#pragma unroll
    for (int j=0;j<8;j++) u[j] = tab[(size_t)r[j]*64 + lane];
#pragma unroll
    for (int j=0;j<8;j++){
      float c = (SKIPSELF && r[j] == selfp) ? 0.f : cf[j];
      ax += c * blo(u[j]);
      ay += c * bhi(u[j]);
    }
  }
  for (; idx < e; ++idx){
    int r = rs[idx] >> shift;
    float c = (SKIPSELF && r == selfp) ? 0.f : cs[idx];
    unsigned u = tab[(size_t)r*64 + lane];
    ax += c * blo(u);
    ay += c * bhi(u);
  }
}

// ---------------- layer-0 aggregate fused with pair max-pool ---------------------------
// one wave per node PAIR (2p, 2p+1); slot ranges adjacent in CSR; writes xp[p] = max
__global__ __launch_bounds__(256) void mp0_kernel(
    const int* __restrict__ starts, const int* __restrict__ rs, const float* __restrict__ c0s,
    const float* __restrict__ dis0, const unsigned* __restrict__ h0b, const float* __restrict__ origin,
    const float* __restrict__ We, const float* __restrict__ be, float* __restrict__ xp, int N2)
{
  int p = blockIdx.x*4 + (threadIdx.x >> 6);
  if (p >= N2) return;
  int lane = threadIdx.x & 63;
  float wself = be[0];
#pragma unroll
  for (int i=0;i<12;i++) wself += We[i];
  int nA = 2*p, nB = 2*p+1;
  int s0 = starts[nA], mid = starts[nB], e1 = starts[nB+1];
  float axA = 0.f, ayA = 0.f, axB = 0.f, ayB = 0.f;
  gather_range<false>(rs, c0s, h0b, lane, s0, mid, 0, -1, axA, ayA);
  gather_range<false>(rs, c0s, h0b, lane, mid, e1, 0, -1, axB, ayB);
  float dnA = dis0[nA], dnB = dis0[nB];
  float csA = dnA*dnA*wself, csB = dnB*dnB*wself;
  unsigned uA = h0b[(size_t)nA*64 + lane];
  unsigned uB = h0b[(size_t)nB*64 + lane];
  const float2 ogA = *(const float2*)(origin + (size_t)nA*128 + lane*2);
  const float2 ogB = *(const float2*)(origin + (size_t)nB*128 + lane*2);
  float oxA = leakyf(dnA*axA + csA*blo(uA) + ogA.x);
  float oyA = leakyf(dnA*ayA + csA*bhi(uA) + ogA.y);
  float oxB = leakyf(dnB*axB + csB*blo(uB) + ogB.x);
  float oyB = leakyf(dnB*ayB + csB*bhi(uB) + ogB.y);
  float2 o2 = {fmaxf(oxA, oxB), fmaxf(oyA, oyB)};
  *(float2*)(xp + (size_t)p*128 + lane*2) = o2;
}

// ---------------- layer-1 aggregate + global max pool, bf16 gather table ----------------
__global__ __launch_bounds__(256) void mp1_kernel(
    const int* __restrict__ starts, const int* __restrict__ rs, const float* __restrict__ c1s,
    const float* __restrict__ dis1, const unsigned* __restrict__ h1b,
    const float* __restrict__ We, const float* __restrict__ be,
    const int* __restrict__ batch_p, unsigned* __restrict__ genc, int N2)
{
  int n = blockIdx.x*4 + (threadIdx.x >> 6);
  if (n >= N2) return;
  int lane = threadIdx.x & 63;
  float wself = be[0];
#pragma unroll
  for (int i=0;i<12;i++) wself += We[i];
  int s = starts[2*n], e = starts[2*n+2];
  float dn = dis1[n];
  float ax = 0.f, ay = 0.f;
  gather_range<true>(rs, c1s, h1b, lane, s, e, 1, n, ax, ay);
  float cs = dn*dn*wself;
  unsigned us = h1b[(size_t)n*64 + lane];
  float ox = leakyf(dn*ax + cs*blo(us));
  float oy = leakyf(dn*ay + cs*bhi(us));
  int b = batch_p[n];
  atomicMax(&genc[(size_t)b*128 + lane*2    ], f32_ord(ox));
  atomicMax(&genc[(size_t)b*128 + lane*2 + 1], f32_ord(oy));
}

// ---------------- head MLP: [64,128] -> [64,64] -> [64] --------------------------------
__global__ __launch_bounds__(256) void head_kernel(
    const unsigned* __restrict__ genc, const float* __restrict__ W1, const float* __restrict__ b1,
    const float* __restrict__ s, const float* __restrict__ t,
    const float* __restrict__ W2, const float* __restrict__ b2, float* __restrict__ out)
{
  __shared__ float g[64][128];
  __shared__ float hh[64][64];
  int tid = threadIdx.x;
  for (int i = tid; i < 64*128; i += 256){
    unsigned u = genc[i];
    unsigned bits = (u & 0x80000000u) ? (u & 0x7FFFFFFFu) : ~u;
    g[i>>7][i&127] = __builtin_bit_cast(float, bits);
  }
  __syncthreads();
  int c = tid & 63;
  int q0 = tid >> 6;
  float accv[16];
#pragma unroll
  for (int i=0;i<16;i++) accv[i] = 0.f;
  for (int k=0;k<128;k++){
    float wv = W1[k*64 + c];
#pragma unroll
    for (int i=0;i<16;i++) accv[i] += g[q0*16+i][k] * wv;
  }
  float sc = s[c], sh = t[c], bb = b1[c];
#pragma unroll
  for (int i=0;i<16;i++){
    float v = (accv[i] + bb)*sc + sh;
    hh[q0*16+i][c] = leakyf(v);
  }
  __syncthreads();
  if (tid < 64){
    float a = b2[0];
    for (int k=0;k<64;k++) a += hh[tid][k]*W2[k];
    out[tid] = a;
  }
}

extern "C" void kernel_launch(void* const* d_in, const int* in_sizes, int n_in,
                              void* d_out, int out_size, void* d_ws, size_t ws_size,
                              hipStream_t stream)
{
  const float* x      = (const float*)d_in[0];
  const float* origin = (const float*)d_in[1];
  const float* ea     = (const float*)d_in[2];
  const int*   ei     = (const int*)d_in[3];
  const int*   batchp = (const int*)d_in[5];
  const float* l0_W1 = (const float*)d_in[6];
  const float* l0_b1 = (const float*)d_in[7];
  const float* l0_s  = (const float*)d_in[8];
  const float* l0_t  = (const float*)d_in[9];
  const float* l0_W2 = (const float*)d_in[10];
  const float* l0_b2 = (const float*)d_in[11];
  const float* l0_We = (const float*)d_in[12];
  const float* l0_be = (const float*)d_in[13];
  const float* l1_W1 = (const float*)d_in[14];
  const float* l1_b1 = (const float*)d_in[15];
  const float* l1_s  = (const float*)d_in[16];
  const float* l1_t  = (const float*)d_in[17];
  const float* l1_W2 = (const float*)d_in[18];
  const float* l1_b2 = (const float*)d_in[19];
  const float* l1_We = (const float*)d_in[20];
  const float* l1_be = (const float*)d_in[21];
  const float* hd_W1 = (const float*)d_in[22];
  const float* hd_b1 = (const float*)d_in[23];
  const float* hd_s  = (const float*)d_in[24];
  const float* hd_t  = (const float*)d_in[25];
  const float* hd_W2 = (const float*)d_in[26];
  const float* hd_b2 = (const float*)d_in[27];

  const int N  = in_sizes[0] / 128;   // 50000
  const int E  = in_sizes[2] / 12;    // 800000
  const int N2 = in_sizes[5];         // 25000
  const int G  = out_size;            // 64
  const int NB = (N + 255) / 256;     // scan blocks

  char* ws = (char*)d_ws;
  size_t off = 0;
  auto alloc = [&](size_t b){ size_t o = off; off += (b + 255) & ~(size_t)255; return o; };
  size_t oA   = alloc((size_t)N*128*4);      // hmid0 / hmid1(25000x256)
  size_t oB   = alloc((size_t)N*128*4);      // [0,12.8M): h0b/h1b bf16 ; [12.8M,25.6M): xp f32
  size_t oW0  = alloc((size_t)E*4);
  size_t oW1  = alloc((size_t)E*4);
  size_t oRS  = alloc((size_t)E*4);
  size_t oC0  = alloc((size_t)E*4);
  size_t oC1  = alloc((size_t)E*4);
  size_t oST  = alloc((size_t)(N+1)*4);
  size_t oCU  = alloc((size_t)N*4);
  size_t oBS  = alloc((size_t)NB*4);
  size_t zbytes = (size_t)N*4 + (size_t)N2*4 + (size_t)N*4 + (size_t)G*128*4;
  size_t oZ   = alloc(zbytes);               // cnt_row0 | cnt_row1 | cnt_col | genc
  size_t oCR0 = oZ;
  size_t oCR1 = oCR0 + (size_t)N*4;
  size_t oCC  = oCR1 + (size_t)N2*4;
  size_t oGE  = oCC  + (size_t)N*4;
  size_t oD0  = alloc((size_t)N*4);
  size_t oD1  = alloc((size_t)N2*4);
  size_t oWsp = alloc((size_t)(16384*2 + 16384*2 + 32768*2 + 32768*2)*2);

  float* regA   = (float*)(ws + oA);
  unsigned* h0b = (unsigned*)(ws + oB);                  // 50000x128 bf16 (as uints)
  unsigned* h1b = (unsigned*)(ws + oB);                  // 25000x128 bf16 (h0b dead)
  float* xp     = (float*)(ws + oB + (size_t)N2*128*4);  // 25000x128 f32
  float* w0     = (float*)(ws + oW0);
  float* w1     = (float*)(ws + oW1);
  int*   rs     = (int*)(ws + oRS);
  float* c0s    = (float*)(ws + oC0);
  float* c1s    = (float*)(ws + oC1);
  int*   starts = (int*)(ws + oST);
  int*   cursor = (int*)(ws + oCU);
  int*   bsum   = (int*)(ws + oBS);
  int*   cr0    = (int*)(ws + oCR0);
  int*   cr1    = (int*)(ws + oCR1);
  int*   cc     = (int*)(ws + oCC);
  unsigned* genc= (unsigned*)(ws + oGE);
  float* dis0   = (float*)(ws + oD0);
  float* dis1   = (float*)(ws + oD1);
  short* l0W1h  = (short*)(ws + oWsp);
  short* l0W1l  = l0W1h + 16384;
  short* l0W2h  = l0W1l + 16384;
  short* l0W2l  = l0W2h + 16384;
  short* l1W1h  = l0W2l + 16384;
  short* l1W1l  = l1W1h + 32768;
  short* l1W2h  = l1W1l + 32768;
  short* l1W2l  = l1W2h + 32768;

  hipMemsetAsync(ws + oZ, 0, zbytes, stream);

  prep_w_kernel<<<64, 256, 0, stream>>>(l0_W1, l0W1h, l0W1l, 128, 128);
  prep_w_kernel<<<64, 256, 0, stream>>>(l0_W2, l0W2h, l0W2l, 128, 128);
  prep_w_kernel<<<128, 256, 0, stream>>>(l1_W1, l1W1h, l1W1l, 128, 256);
  prep_w_kernel<<<128, 256, 0, stream>>>(l1_W2, l1W2h, l1W2l, 256, 128);

  edge_pass_kernel<<<(E+255)/256, 256, 0, stream>>>(ei, ea, l0_We, l0_be, l1_We, l1_be,
                                                    w0, w1, cr0, cr1, cc, E);
  dis_kernel<<<(N+255)/256, 256, 0, stream>>>(cr0, dis0, N);
  dis_kernel<<<(N2+255)/256, 256, 0, stream>>>(cr1, dis1, N2);
  scan_partial_kernel<<<NB, 256, 0, stream>>>(cc, bsum, N);
  scan_bsums_kernel<<<1, 64, 0, stream>>>(bsum, NB);
  scan_final_kernel<<<NB, 256, 0, stream>>>(cc, bsum, starts, cursor, N);
  fill_kernel<<<(E+255)/256, 256, 0, stream>>>(ei, w0, w1, dis0, dis1, cursor, rs, c0s, c1s, E);

  // MLP0: x -> hmid0(regA) -> h0b (bf16)
  gemm_split<8><<<(N+63)/64, 256, 0, stream>>>(x, l0W1h, l0W1l, l0_b1, l0_s, l0_t, regA, N, 128, 1);
  gemm_split<8><<<(N+63)/64, 256, 0, stream>>>(regA, l0W2h, l0W2l, l0_b2, nullptr, nullptr, h0b, N, 128, 2);
  // aggregate layer0 fused with pair pool -> xp
  mp0_kernel<<<(N2+3)/4, 256, 0, stream>>>(starts, rs, c0s, dis0, h0b, origin, l0_We, l0_be, xp, N2);
  // MLP1: xp -> hmid1(regA, 25000x256) -> h1b (bf16)
  gemm_split<16><<<(N2+63)/64, 256, 0, stream>>>(xp, l1W1h, l1W1l, l1_b1, l1_s, l1_t, regA, N2, 128, 1);
  gemm_split<8><<<(N2+63)/64, 256, 0, stream>>>(regA, l1W2h, l1W2l, l1_b2, nullptr, nullptr, h1b, N2, 256, 2);
  // aggregate layer1 + global max pool
  mp1_kernel<<<(N2+3)/4, 256, 0, stream>>>(starts, rs, c1s, dis1, h1b, l1_We, l1_be, batchp, genc, N2);
  // head
  head_kernel<<<1, 256, 0, stream>>>(genc, hd_W1, hd_b1, hd_s, hd_t, hd_W2, hd_b2, (float*)d_out);
}

// Round 4
// 383.862 us; speedup vs baseline: 1.4524x; 1.0691x over previous
//
#include <hip/hip_runtime.h>

typedef __attribute__((ext_vector_type(4))) float f32x4;
typedef __attribute__((ext_vector_type(8))) short bf16x8;

__device__ __forceinline__ unsigned short f32_to_bf16_rne(float f){
  unsigned u = __builtin_bit_cast(unsigned, f);
  unsigned r = u + 0x7FFFu + ((u >> 16) & 1u);
  return (unsigned short)(r >> 16);
}
__device__ __forceinline__ float bf16_hi_to_f32(unsigned short h){
  unsigned u = ((unsigned)h) << 16;
  return __builtin_bit_cast(float, u);
}
__device__ __forceinline__ float blo(unsigned u){ return bf16_hi_to_f32((unsigned short)(u & 0xFFFF)); }
__device__ __forceinline__ float bhi(unsigned u){ return bf16_hi_to_f32((unsigned short)(u >> 16)); }
__device__ __forceinline__ float leakyf(float v){ return v > 0.f ? v : 0.01f*v; }
__device__ __forceinline__ unsigned f32_ord(float f){
  unsigned u = __builtin_bit_cast(unsigned, f);
  return (u & 0x80000000u) ? ~u : (u | 0x80000000u);
}

// ---------------- weight pre-split into MFMA B-fragment layout (hi/lo bf16) -------------
__global__ void prep_w_kernel(const float* __restrict__ W, short* __restrict__ Wh,
                              short* __restrict__ Wl, int K, int N)
{
  int total = K*N;
  int NF = N >> 4;
  for (int i = blockIdx.x*blockDim.x + threadIdx.x; i < total; i += gridDim.x*blockDim.x){
    int k = i / N, n = i % N;
    float w = W[i];
    unsigned short h = f32_to_bf16_rne(w);
    unsigned short l = f32_to_bf16_rne(w - bf16_hi_to_f32(h));
    int kb = k >> 5, kr = k & 31, cb = n >> 4;
    int lanei = ((kr >> 3) << 4) | (n & 15);
    size_t dst = (((size_t)(kb*NF + cb))*64 + lanei)*8 + (kr & 7);
    Wh[dst] = (short)h; Wl[dst] = (short)l;
  }
}

// ---------------- edge histogram: 2 packed u64 atomics per edge, reads ei only ----------
// pk[p] fields: [0:16) col-pair count, [16:32) row0 even, [32:48) row0 odd, [48:64) row1
__global__ void edge_hist_kernel(const int* __restrict__ ei,
                                 unsigned long long* __restrict__ pk, int E)
{
  int e = blockIdx.x*blockDim.x + threadIdx.x;
  if (e >= E) return;
  int r = ei[e], c = ei[E+e];
  atomicAdd(&pk[c>>1], 1ull);
  unsigned long long enc = (1ull << 16) << ((r & 1) << 4);   // 1<<16 or 1<<32
  if ((r>>1) != (c>>1)) enc += (1ull << 48);
  atomicAdd(&pk[r>>1], enc);
}

// ---------------- dis from packed counts ------------------------------------------------
__global__ void dis_kernel(const unsigned long long* __restrict__ pk,
                           float* __restrict__ dis0, float* __restrict__ dis1, int N2)
{
  int p = blockIdx.x*blockDim.x + threadIdx.x;
  if (p >= N2) return;
  unsigned long long v = pk[p];
  float2 d0 = { rsqrtf((float)((v>>16) & 0xFFFF) + 1.0f),
                rsqrtf((float)((v>>32) & 0xFFFF) + 1.0f) };
  *(float2*)(dis0 + 2*p) = d0;
  dis1[p] = rsqrtf((float)(v>>48) + 1.0f);
}

// ---------------- 3-pass parallel exclusive scan over pk's col-pair field ---------------
__global__ void scan_partial_kernel(const unsigned long long* __restrict__ pk,
                                    int* __restrict__ bsum, int N)
{
  __shared__ int ws[4];
  int t = threadIdx.x, lane = t & 63, wv = t >> 6;
  int i = blockIdx.x*256 + t;
  int v = (i < N) ? (int)(pk[i] & 0xFFFF) : 0;
#pragma unroll
  for (int d = 1; d < 64; d <<= 1) v += __shfl_xor(v, d);
  if (lane == 0) ws[wv] = v;
  __syncthreads();
  if (t == 0) bsum[blockIdx.x] = ws[0]+ws[1]+ws[2]+ws[3];
}

__global__ void scan_bsums_kernel(int* __restrict__ bsum, int NB)
{
  int lane = threadIdx.x;  // 64 threads, 1 wave
  int carry = 0;
  for (int base = 0; base < NB; base += 64){
    int i = base + lane;
    int v = (i < NB) ? bsum[i] : 0;
    int x = v;
#pragma unroll
    for (int d = 1; d < 64; d <<= 1){
      int y = __shfl_up(x, d);
      if (lane >= d) x += y;
    }
    if (i < NB) bsum[i] = x - v + carry;   // exclusive
    carry += __shfl(x, 63);
  }
}

__global__ void scan_final_kernel(const unsigned long long* __restrict__ pk,
                                  const int* __restrict__ bsum,
                                  int* __restrict__ starts, int* __restrict__ cursor, int N)
{
  __shared__ int wsum[4];
  int t = threadIdx.x, lane = t & 63, wv = t >> 6;
  int i = blockIdx.x*256 + t;
  int v = (i < N) ? (int)(pk[i] & 0xFFFF) : 0;
  int x = v;
#pragma unroll
  for (int d = 1; d < 64; d <<= 1){
    int y = __shfl_up(x, d);
    if (lane >= d) x += y;
  }
  if (lane == 63) wsum[wv] = x;
  __syncthreads();
  int woff = 0;
#pragma unroll
  for (int j = 0; j < 4; j++) if (j < wv) woff += wsum[j];
  int base = bsum[blockIdx.x] + woff;
  if (i < N){
    starts[i+1] = base + x;
    cursor[i]   = base + x - v;
  }
  if (blockIdx.x == 0 && t == 0) starts[0] = 0;
}

// ---------------- CSR fill: edge weights inline, parity flag in rs bit31 ----------------
__global__ void fill_kernel(const int* __restrict__ ei, const float* __restrict__ ea,
                            const float* __restrict__ We0, const float* __restrict__ be0,
                            const float* __restrict__ We1, const float* __restrict__ be1,
                            const float* __restrict__ dis0, const float* __restrict__ dis1,
                            int* __restrict__ cursor, int* __restrict__ rs,
                            float* __restrict__ c0s, float* __restrict__ c1s, int E)
{
  float A0[12], A1[12];
#pragma unroll
  for (int i=0;i<12;i++){ A0[i]=We0[i]; A1[i]=We1[i]; }
  float b0 = be0[0], b1 = be1[0];
  int e = blockIdx.x*blockDim.x + threadIdx.x;
  if (e >= E) return;
  int r = ei[e], c = ei[E+e];
  const f32x4* ap = (const f32x4*)(ea + (size_t)e*12);
  f32x4 v0 = ap[0], v1 = ap[1], v2 = ap[2];
  float s0 = b0, s1 = b1;
#pragma unroll
  for (int j=0;j<4;j++){ s0 += v0[j]*A0[j];   s1 += v0[j]*A1[j]; }
#pragma unroll
  for (int j=0;j<4;j++){ s0 += v1[j]*A0[4+j]; s1 += v1[j]*A1[4+j]; }
#pragma unroll
  for (int j=0;j<4;j++){ s0 += v2[j]*A0[8+j]; s1 += v2[j]*A1[8+j]; }
  int pos = atomicAdd(&cursor[c>>1], 1);
  rs[pos]  = r | ((c & 1) << 31);
  c0s[pos] = dis0[r] * s0;
  c1s[pos] = dis1[r>>1] * s1;
}

// ---------------- split-bf16 MFMA GEMM: Y = epilogue(X @ W + b) -------------------------
// flags&1: y = leaky(y*scale + shift);  flags&2: store bf16 (ushort) else f32
template<int NF>
__global__ __launch_bounds__(256) void gemm_split(
    const float* __restrict__ X, const short* __restrict__ Wh, const short* __restrict__ Wl,
    const float* __restrict__ bias, const float* __restrict__ scale, const float* __restrict__ shift,
    void* __restrict__ Yv, int M, int K, int flags)
{
  const int Nn = NF*16;
  int w = threadIdx.x >> 6, lane = threadIdx.x & 63;
  int r0 = blockIdx.x*64 + w*16;
  int arow = r0 + (lane & 15);
  long arow_c = (arow < M) ? arow : (M-1);
  int kHi = (lane >> 4) << 3;
  f32x4 acc[NF];
#pragma unroll
  for (int i=0;i<NF;i++){
#pragma unroll
    for (int j=0;j<4;j++) acc[i][j] = 0.f;
  }
  int KB = K >> 5;
  const float* aprow = X + arow_c*(long)K + kHi;
  for (int kb=0; kb<KB; ++kb){
    const float* ap = aprow + kb*32;
    f32x4 a0 = *(const f32x4*)ap;
    f32x4 a1 = *(const f32x4*)(ap+4);
    bf16x8 ah, al;
#pragma unroll
    for (int j=0;j<8;j++){
      float f = (j<4) ? a0[j] : a1[j-4];
      unsigned short h = f32_to_bf16_rne(f);
      ah[j] = (short)h;
      al[j] = (short)f32_to_bf16_rne(f - bf16_hi_to_f32(h));
    }
    const short* bp  = Wh + ((size_t)kb*NF*64 + lane)*8;
    const short* bpl = Wl + ((size_t)kb*NF*64 + lane)*8;
#pragma unroll
    for (int cb=0; cb<NF; ++cb){
      bf16x8 bh = *(const bf16x8*)(bp  + (size_t)cb*512);
      bf16x8 bl = *(const bf16x8*)(bpl + (size_t)cb*512);
      acc[cb] = __builtin_amdgcn_mfma_f32_16x16x32_bf16(ah, bh, acc[cb], 0,0,0);
      acc[cb] = __builtin_amdgcn_mfma_f32_16x16x32_bf16(al, bh, acc[cb], 0,0,0);
      acc[cb] = __builtin_amdgcn_mfma_f32_16x16x32_bf16(ah, bl, acc[cb], 0,0,0);
    }
  }
  int crow = r0 + ((lane >> 4) << 2);
  int ccol = lane & 15;
  float* Yf = (float*)Yv;
  unsigned short* Yb = (unsigned short*)Yv;
#pragma unroll
  for (int cb=0; cb<NF; ++cb){
    int c = cb*16 + ccol;
    float b = bias[c];
    float sc = 1.f, sh = 0.f;
    if (flags & 1){ sc = scale[c]; sh = shift[c]; }
#pragma unroll
    for (int r=0;r<4;r++){
      int row = crow + r;
      if (row < M){
        float v = acc[cb][r] + b;
        if (flags & 1){ v = v*sc + sh; v = leakyf(v); }
        if (flags & 2) Yb[(size_t)row*Nn + c] = f32_to_bf16_rne(v);
        else           Yf[(size_t)row*Nn + c] = v;
      }
    }
  }
}

// ---------------- layer-0 aggregate fused with pair max-pool (flag-select A/B) ----------
__global__ __launch_bounds__(256) void mp0_kernel(
    const int* __restrict__ starts, const int* __restrict__ rs, const float* __restrict__ c0s,
    const float* __restrict__ dis0, const unsigned* __restrict__ h0b, const float* __restrict__ origin,
    const float* __restrict__ We, const float* __restrict__ be, float* __restrict__ xp, int N2)
{
  int p = blockIdx.x*4 + (threadIdx.x >> 6);
  if (p >= N2) return;
  int lane = threadIdx.x & 63;
  float wself = be[0];
#pragma unroll
  for (int i=0;i<12;i++) wself += We[i];
  int s = starts[p], e = starts[p+1];
  float axA = 0.f, ayA = 0.f, axB = 0.f, ayB = 0.f;
  int idx = s;
  for (; idx + 8 <= e; idx += 8){
    int rv[8]; float cf[8]; unsigned u[8];
#pragma unroll
    for (int j=0;j<8;j++){ rv[j] = rs[idx+j]; cf[j] = c0s[idx+j]; }
#pragma unroll
    for (int j=0;j<8;j++) u[j] = h0b[(size_t)(rv[j] & 0x7FFFFFFF)*64 + lane];
#pragma unroll
    for (int j=0;j<8;j++){
      float cB = (rv[j] < 0) ? cf[j] : 0.f;
      float cA = (rv[j] < 0) ? 0.f : cf[j];
      float lo = blo(u[j]), hi = bhi(u[j]);
      axA += cA*lo; ayA += cA*hi; axB += cB*lo; ayB += cB*hi;
    }
  }
  for (; idx < e; ++idx){
    int rv = rs[idx]; float cf = c0s[idx];
    unsigned u = h0b[(size_t)(rv & 0x7FFFFFFF)*64 + lane];
    float cB = (rv < 0) ? cf : 0.f;
    float cA = (rv < 0) ? 0.f : cf;
    float lo = blo(u), hi = bhi(u);
    axA += cA*lo; ayA += cA*hi; axB += cB*lo; ayB += cB*hi;
  }
  int nA = 2*p, nB = 2*p+1;
  float dnA = dis0[nA], dnB = dis0[nB];
  float csA = dnA*dnA*wself, csB = dnB*dnB*wself;
  unsigned uA = h0b[(size_t)nA*64 + lane];
  unsigned uB = h0b[(size_t)nB*64 + lane];
  const float2 ogA = *(const float2*)(origin + (size_t)nA*128 + lane*2);
  const float2 ogB = *(const float2*)(origin + (size_t)nB*128 + lane*2);
  float oxA = leakyf(dnA*axA + csA*blo(uA) + ogA.x);
  float oyA = leakyf(dnA*ayA + csA*bhi(uA) + ogA.y);
  float oxB = leakyf(dnB*axB + csB*blo(uB) + ogB.x);
  float oyB = leakyf(dnB*ayB + csB*bhi(uB) + ogB.y);
  float2 o2 = {fmaxf(oxA, oxB), fmaxf(oyA, oyB)};
  *(float2*)(xp + (size_t)p*128 + lane*2) = o2;
}

// ---------------- layer-1 aggregate + global max pool ----------------------------------
__global__ __launch_bounds__(256) void mp1_kernel(
    const int* __restrict__ starts, const int* __restrict__ rs, const float* __restrict__ c1s,
    const float* __restrict__ dis1, const unsigned* __restrict__ h1b,
    const float* __restrict__ We, const float* __restrict__ be,
    const int* __restrict__ batch_p, unsigned* __restrict__ genc, int N2)
{
  int n = blockIdx.x*4 + (threadIdx.x >> 6);
  if (n >= N2) return;
  int lane = threadIdx.x & 63;
  float wself = be[0];
#pragma unroll
  for (int i=0;i<12;i++) wself += We[i];
  int s = starts[n], e = starts[n+1];
  float dn = dis1[n];
  float ax = 0.f, ay = 0.f;
  int idx = s;
  for (; idx + 8 <= e; idx += 8){
    int rp[8]; float cf[8]; unsigned u[8];
#pragma unroll
    for (int j=0;j<8;j++){ rp[j] = (rs[idx+j] & 0x7FFFFFFF) >> 1; cf[j] = c1s[idx+j]; }
#pragma unroll
    for (int j=0;j<8;j++) u[j] = h1b[(size_t)rp[j]*64 + lane];
#pragma unroll
    for (int j=0;j<8;j++){
      float c = (rp[j] == n) ? 0.f : cf[j];
      ax += c * blo(u[j]);
      ay += c * bhi(u[j]);
    }
  }
  for (; idx < e; ++idx){
    int rp = (rs[idx] & 0x7FFFFFFF) >> 1;
    float c = (rp == n) ? 0.f : c1s[idx];
    unsigned u = h1b[(size_t)rp*64 + lane];
    ax += c * blo(u);
    ay += c * bhi(u);
  }
  float cs = dn*dn*wself;
  unsigned us = h1b[(size_t)n*64 + lane];
  float ox = leakyf(dn*ax + cs*blo(us));
  float oy = leakyf(dn*ay + cs*bhi(us));
  int b = batch_p[n];
  atomicMax(&genc[(size_t)b*128 + lane*2    ], f32_ord(ox));
  atomicMax(&genc[(size_t)b*128 + lane*2 + 1], f32_ord(oy));
}

// ---------------- head MLP: [64,128] -> [64,64] -> [64] --------------------------------
__global__ __launch_bounds__(256) void head_kernel(
    const unsigned* __restrict__ genc, const float* __restrict__ W1, const float* __restrict__ b1,
    const float* __restrict__ s, const float* __restrict__ t,
    const float* __restrict__ W2, const float* __restrict__ b2, float* __restrict__ out)
{
  __shared__ float g[64][128];
  __shared__ float hh[64][64];
  int tid = threadIdx.x;
  for (int i = tid; i < 64*128; i += 256){
    unsigned u = genc[i];
    unsigned bits = (u & 0x80000000u) ? (u & 0x7FFFFFFFu) : ~u;
    g[i>>7][i&127] = __builtin_bit_cast(float, bits);
  }
  __syncthreads();
  int c = tid & 63;
  int q0 = tid >> 6;
  float accv[16];
#pragma unroll
  for (int i=0;i<16;i++) accv[i] = 0.f;
  for (int k=0;k<128;k++){
    float wv = W1[k*64 + c];
#pragma unroll
    for (int i=0;i<16;i++) accv[i] += g[q0*16+i][k] * wv;
  }
  float sc = s[c], sh = t[c], bb = b1[c];
#pragma unroll
  for (int i=0;i<16;i++){
    float v = (accv[i] + bb)*sc + sh;
    hh[q0*16+i][c] = leakyf(v);
  }
  __syncthreads();
  if (tid < 64){
    float a = b2[0];
    for (int k=0;k<64;k++) a += hh[tid][k]*W2[k];
    out[tid] = a;
  }
}

extern "C" void kernel_launch(void* const* d_in, const int* in_sizes, int n_in,
                              void* d_out, int out_size, void* d_ws, size_t ws_size,
                              hipStream_t stream)
{
  const float* x      = (const float*)d_in[0];
  const float* origin = (const float*)d_in[1];
  const float* ea     = (const float*)d_in[2];
  const int*   ei     = (const int*)d_in[3];
  const int*   batchp = (const int*)d_in[5];
  const float* l0_W1 = (const float*)d_in[6];
  const float* l0_b1 = (const float*)d_in[7];
  const float* l0_s  = (const float*)d_in[8];
  const float* l0_t  = (const float*)d_in[9];
  const float* l0_W2 = (const float*)d_in[10];
  const float* l0_b2 = (const float*)d_in[11];
  const float* l0_We = (const float*)d_in[12];
  const float* l0_be = (const float*)d_in[13];
  const float* l1_W1 = (const float*)d_in[14];
  const float* l1_b1 = (const float*)d_in[15];
  const float* l1_s  = (const float*)d_in[16];
  const float* l1_t  = (const float*)d_in[17];
  const float* l1_W2 = (const float*)d_in[18];
  const float* l1_b2 = (const float*)d_in[19];
  const float* l1_We = (const float*)d_in[20];
  const float* l1_be = (const float*)d_in[21];
  const float* hd_W1 = (const float*)d_in[22];
  const float* hd_b1 = (const float*)d_in[23];
  const float* hd_s  = (const float*)d_in[24];
  const float* hd_t  = (const float*)d_in[25];
  const float* hd_W2 = (const float*)d_in[26];
  const float* hd_b2 = (const float*)d_in[27];

  const int N  = in_sizes[0] / 128;   // 50000
  const int E  = in_sizes[2] / 12;    // 800000
  const int N2 = in_sizes[5];         // 25000
  const int G  = out_size;            // 64
  const int NB = (N2 + 255) / 256;    // scan blocks over pair bins

  char* ws = (char*)d_ws;
  size_t off = 0;
  auto alloc = [&](size_t b){ size_t o = off; off += (b + 255) & ~(size_t)255; return o; };
  size_t oA   = alloc((size_t)N*128*4);      // hmid0 / hmid1(25000x256)
  size_t oB   = alloc((size_t)N*128*4);      // [0,12.8M): h0b/h1b bf16 ; [12.8M,25.6M): xp f32
  size_t oRS  = alloc((size_t)E*4);
  size_t oC0  = alloc((size_t)E*4);
  size_t oC1  = alloc((size_t)E*4);
  size_t oST  = alloc((size_t)(N2+1)*4);
  size_t oCU  = alloc((size_t)N2*4);
  size_t oBS  = alloc((size_t)NB*4);
  size_t zbytes = (size_t)N2*8 + (size_t)G*128*4;
  size_t oZ   = alloc(zbytes);               // pk | genc
  size_t oPK  = oZ;
  size_t oGE  = oPK + (size_t)N2*8;
  size_t oD0  = alloc((size_t)N*4);
  size_t oD1  = alloc((size_t)N2*4);
  size_t oWsp = alloc((size_t)(16384*2 + 16384*2 + 32768*2 + 32768*2)*2);

  float* regA   = (float*)(ws + oA);
  unsigned* h0b = (unsigned*)(ws + oB);                  // 50000x128 bf16 (as uints)
  unsigned* h1b = (unsigned*)(ws + oB);                  // 25000x128 bf16 (h0b dead)
  float* xp     = (float*)(ws + oB + (size_t)N2*128*4);  // 25000x128 f32
  int*   rs     = (int*)(ws + oRS);
  float* c0s    = (float*)(ws + oC0);
  float* c1s    = (float*)(ws + oC1);
  int*   starts = (int*)(ws + oST);
  int*   cursor = (int*)(ws + oCU);
  int*   bsum   = (int*)(ws + oBS);
  unsigned long long* pk = (unsigned long long*)(ws + oPK);
  unsigned* genc= (unsigned*)(ws + oGE);
  float* dis0   = (float*)(ws + oD0);
  float* dis1   = (float*)(ws + oD1);
  short* l0W1h  = (short*)(ws + oWsp);
  short* l0W1l  = l0W1h + 16384;
  short* l0W2h  = l0W1l + 16384;
  short* l0W2l  = l0W2h + 16384;
  short* l1W1h  = l0W2l + 16384;
  short* l1W1l  = l1W1h + 32768;
  short* l1W2h  = l1W1l + 32768;
  short* l1W2l  = l1W2h + 32768;

  hipMemsetAsync(ws + oZ, 0, zbytes, stream);

  prep_w_kernel<<<64, 256, 0, stream>>>(l0_W1, l0W1h, l0W1l, 128, 128);
  prep_w_kernel<<<64, 256, 0, stream>>>(l0_W2, l0W2h, l0W2l, 128, 128);
  prep_w_kernel<<<128, 256, 0, stream>>>(l1_W1, l1W1h, l1W1l, 128, 256);
  prep_w_kernel<<<128, 256, 0, stream>>>(l1_W2, l1W2h, l1W2l, 256, 128);

  edge_hist_kernel<<<(E+255)/256, 256, 0, stream>>>(ei, pk, E);
  dis_kernel<<<(N2+255)/256, 256, 0, stream>>>(pk, dis0, dis1, N2);
  scan_partial_kernel<<<NB, 256, 0, stream>>>(pk, bsum, N2);
  scan_bsums_kernel<<<1, 64, 0, stream>>>(bsum, NB);
  scan_final_kernel<<<NB, 256, 0, stream>>>(pk, bsum, starts, cursor, N2);
  fill_kernel<<<(E+255)/256, 256, 0, stream>>>(ei, ea, l0_We, l0_be, l1_We, l1_be,
                                               dis0, dis1, cursor, rs, c0s, c1s, E);

  // MLP0: x -> hmid0(regA) -> h0b (bf16)
  gemm_split<8><<<(N+63)/64, 256, 0, stream>>>(x, l0W1h, l0W1l, l0_b1, l0_s, l0_t, regA, N, 128, 1);
  gemm_split<8><<<(N+63)/64, 256, 0, stream>>>(regA, l0W2h, l0W2l, l0_b2, nullptr, nullptr, h0b, N, 128, 2);
  // aggregate layer0 fused with pair pool -> xp
  mp0_kernel<<<(N2+3)/4, 256, 0, stream>>>(starts, rs, c0s, dis0, h0b, origin, l0_We, l0_be, xp, N2);
  // MLP1: xp -> hmid1(regA, 25000x256) -> h1b (bf16)
  gemm_split<16><<<(N2+63)/64, 256, 0, stream>>>(xp, l1W1h, l1W1l, l1_b1, l1_s, l1_t, regA, N2, 128, 1);
  gemm_split<8><<<(N2+63)/64, 256, 0, stream>>>(regA, l1W2h, l1W2l, l1_b2, nullptr, nullptr, h1b, N2, 256, 2);
  // aggregate layer1 + global max pool
  mp1_kernel<<<(N2+3)/4, 256, 0, stream>>>(starts, rs, c1s, dis1, h1b, l1_We, l1_be, batchp, genc, N2);
  // head
  head_kernel<<<1, 256, 0, stream>>>(genc, hd_W1, hd_b1, hd_s, hd_t, hd_W2, hd_b2, (float*)d_out);
}

// Round 5
// 360.902 us; speedup vs baseline: 1.5447x; 1.0636x over previous
//
#include <hip/hip_runtime.h>

typedef __attribute__((ext_vector_type(4))) float f32x4;
typedef __attribute__((ext_vector_type(8))) short bf16x8;

__device__ __forceinline__ unsigned short f32_to_bf16_rne(float f){
  unsigned u = __builtin_bit_cast(unsigned, f);
  unsigned r = u + 0x7FFFu + ((u >> 16) & 1u);
  return (unsigned short)(r >> 16);
}
__device__ __forceinline__ float bf16_hi_to_f32(unsigned short h){
  unsigned u = ((unsigned)h) << 16;
  return __builtin_bit_cast(float, u);
}
__device__ __forceinline__ float blo(unsigned u){ return bf16_hi_to_f32((unsigned short)(u & 0xFFFF)); }
__device__ __forceinline__ float bhi(unsigned u){ return bf16_hi_to_f32((unsigned short)(u >> 16)); }
__device__ __forceinline__ float leakyf(float v){ return v > 0.f ? v : 0.01f*v; }
__device__ __forceinline__ unsigned f32_ord(float f){
  unsigned u = __builtin_bit_cast(unsigned, f);
  return (u & 0x80000000u) ? ~u : (u | 0x80000000u);
}

#define PKS 4   // pk stride in u64 (32B: one bin per sector)

// ---------------- weight pre-split into MFMA B-fragment layout (hi/lo bf16) -------------
__global__ void prep_w_kernel(const float* __restrict__ W, short* __restrict__ Wh,
                              short* __restrict__ Wl, int K, int N)
{
  int total = K*N;
  int NF = N >> 4;
  for (int i = blockIdx.x*blockDim.x + threadIdx.x; i < total; i += gridDim.x*blockDim.x){
    int k = i / N, n = i % N;
    float w = W[i];
    unsigned short h = f32_to_bf16_rne(w);
    unsigned short l = f32_to_bf16_rne(w - bf16_hi_to_f32(h));
    int kb = k >> 5, kr = k & 31, cb = n >> 4;
    int lanei = ((kr >> 3) << 4) | (n & 15);
    size_t dst = (((size_t)(kb*NF + cb))*64 + lanei)*8 + (kr & 7);
    Wh[dst] = (short)h; Wl[dst] = (short)l;
  }
}

// ---------------- edge histogram: 2 padded u64 atomics per edge + col rank out ----------
// pk[p*PKS] fields: [0:16) col-pair count, [16:32) row0 even, [32:48) row0 odd, [48:64) row1
__global__ void edge_hist_kernel(const int* __restrict__ ei,
                                 unsigned long long* __restrict__ pk,
                                 unsigned short* __restrict__ rank, int E)
{
  int base = (blockIdx.x*blockDim.x + threadIdx.x)*4;
  if (base >= E) return;
  int n = min(4, E - base);
  int r[4], c[4];
#pragma unroll
  for (int j=0;j<4;j++) if (j < n){ r[j] = ei[base+j]; c[j] = ei[E+base+j]; }
  unsigned long long old[4];
#pragma unroll
  for (int j=0;j<4;j++) if (j < n){
    unsigned long long enc = (1ull << 16) << ((r[j] & 1) << 4);
    if ((r[j]>>1) != (c[j]>>1)) enc += (1ull << 48);
    atomicAdd(&pk[(size_t)(r[j]>>1)*PKS], enc);
  }
#pragma unroll
  for (int j=0;j<4;j++) if (j < n) old[j] = atomicAdd(&pk[(size_t)(c[j]>>1)*PKS], 1ull);
#pragma unroll
  for (int j=0;j<4;j++) if (j < n) rank[base+j] = (unsigned short)(old[j] & 0xFFFF);
}

// ---------------- dis from packed counts ------------------------------------------------
__global__ void dis_kernel(const unsigned long long* __restrict__ pk,
                           float* __restrict__ dis0, float* __restrict__ dis1, int N2)
{
  int p = blockIdx.x*blockDim.x + threadIdx.x;
  if (p >= N2) return;
  unsigned long long v = pk[(size_t)p*PKS];
  float2 d0 = { rsqrtf((float)((v>>16) & 0xFFFF) + 1.0f),
                rsqrtf((float)((v>>32) & 0xFFFF) + 1.0f) };
  *(float2*)(dis0 + 2*p) = d0;
  dis1[p] = rsqrtf((float)(v>>48) + 1.0f);
}

// ---------------- 3-pass parallel exclusive scan over pk's col-pair field ---------------
__global__ void scan_partial_kernel(const unsigned long long* __restrict__ pk,
                                    int* __restrict__ bsum, int N)
{
  __shared__ int ws[4];
  int t = threadIdx.x, lane = t & 63, wv = t >> 6;
  int i = blockIdx.x*256 + t;
  int v = (i < N) ? (int)(pk[(size_t)i*PKS] & 0xFFFF) : 0;
#pragma unroll
  for (int d = 1; d < 64; d <<= 1) v += __shfl_xor(v, d);
  if (lane == 0) ws[wv] = v;
  __syncthreads();
  if (t == 0) bsum[blockIdx.x] = ws[0]+ws[1]+ws[2]+ws[3];
}

__global__ void scan_bsums_kernel(int* __restrict__ bsum, int NB)
{
  int lane = threadIdx.x;  // 64 threads, 1 wave
  int carry = 0;
  for (int base = 0; base < NB; base += 64){
    int i = base + lane;
    int v = (i < NB) ? bsum[i] : 0;
    int x = v;
#pragma unroll
    for (int d = 1; d < 64; d <<= 1){
      int y = __shfl_up(x, d);
      if (lane >= d) x += y;
    }
    if (i < NB) bsum[i] = x - v + carry;   // exclusive
    carry += __shfl(x, 63);
  }
}

__global__ void scan_final_kernel(const unsigned long long* __restrict__ pk,
                                  const int* __restrict__ bsum,
                                  int* __restrict__ starts, int N)
{
  __shared__ int wsum[4];
  int t = threadIdx.x, lane = t & 63, wv = t >> 6;
  int i = blockIdx.x*256 + t;
  int v = (i < N) ? (int)(pk[(size_t)i*PKS] & 0xFFFF) : 0;
  int x = v;
#pragma unroll
  for (int d = 1; d < 64; d <<= 1){
    int y = __shfl_up(x, d);
    if (lane >= d) x += y;
  }
  if (lane == 63) wsum[wv] = x;
  __syncthreads();
  int woff = 0;
#pragma unroll
  for (int j = 0; j < 4; j++) if (j < wv) woff += wsum[j];
  int base = bsum[blockIdx.x] + woff;
  if (i < N) starts[i+1] = base + x;
  if (blockIdx.x == 0 && t == 0) starts[0] = 0;
}

// ---------------- CSR fill: atomic-free via precomputed rank ---------------------------
__global__ void fill_kernel(const int* __restrict__ ei, const float* __restrict__ ea,
                            const float* __restrict__ We0, const float* __restrict__ be0,
                            const float* __restrict__ We1, const float* __restrict__ be1,
                            const int* __restrict__ starts, const unsigned short* __restrict__ rank,
                            int* __restrict__ rs,
                            float* __restrict__ c0s, float* __restrict__ c1s, int E)
{
  float A0[12], A1[12];
#pragma unroll
  for (int i=0;i<12;i++){ A0[i]=We0[i]; A1[i]=We1[i]; }
  float b0 = be0[0], b1 = be1[0];
  int e = blockIdx.x*blockDim.x + threadIdx.x;
  if (e >= E) return;
  int r = ei[e], c = ei[E+e];
  const f32x4* ap = (const f32x4*)(ea + (size_t)e*12);
  f32x4 v0 = ap[0], v1 = ap[1], v2 = ap[2];
  float s0 = b0, s1 = b1;
#pragma unroll
  for (int j=0;j<4;j++){ s0 += v0[j]*A0[j];   s1 += v0[j]*A1[j]; }
#pragma unroll
  for (int j=0;j<4;j++){ s0 += v1[j]*A0[4+j]; s1 += v1[j]*A1[4+j]; }
#pragma unroll
  for (int j=0;j<4;j++){ s0 += v2[j]*A0[8+j]; s1 += v2[j]*A1[8+j]; }
  int pos = starts[c>>1] + rank[e];
  rs[pos]  = r | ((c & 1) << 31);
  c0s[pos] = s0;
  c1s[pos] = s1;
}

// ---------------- split-bf16 MFMA GEMM: Y = epilogue(X @ W + b) -------------------------
// flags&1: y = leaky(y*scale + shift);  flags&2: store bf16;  flags&4: y *= rowscale[row]
template<int NF>
__global__ __launch_bounds__(256) void gemm_split(
    const float* __restrict__ X, const short* __restrict__ Wh, const short* __restrict__ Wl,
    const float* __restrict__ bias, const float* __restrict__ scale, const float* __restrict__ shift,
    const float* __restrict__ rowscale,
    void* __restrict__ Yv, int M, int K, int flags)
{
  const int Nn = NF*16;
  int w = threadIdx.x >> 6, lane = threadIdx.x & 63;
  int r0 = blockIdx.x*64 + w*16;
  int arow = r0 + (lane & 15);
  long arow_c = (arow < M) ? arow : (M-1);
  int kHi = (lane >> 4) << 3;
  f32x4 acc[NF];
#pragma unroll
  for (int i=0;i<NF;i++){
#pragma unroll
    for (int j=0;j<4;j++) acc[i][j] = 0.f;
  }
  int KB = K >> 5;
  const float* aprow = X + arow_c*(long)K + kHi;
  for (int kb=0; kb<KB; ++kb){
    const float* ap = aprow + kb*32;
    f32x4 a0 = *(const f32x4*)ap;
    f32x4 a1 = *(const f32x4*)(ap+4);
    bf16x8 ah, al;
#pragma unroll
    for (int j=0;j<8;j++){
      float f = (j<4) ? a0[j] : a1[j-4];
      unsigned short h = f32_to_bf16_rne(f);
      ah[j] = (short)h;
      al[j] = (short)f32_to_bf16_rne(f - bf16_hi_to_f32(h));
    }
    const short* bp  = Wh + ((size_t)kb*NF*64 + lane)*8;
    const short* bpl = Wl + ((size_t)kb*NF*64 + lane)*8;
#pragma unroll
    for (int cb=0; cb<NF; ++cb){
      bf16x8 bh = *(const bf16x8*)(bp  + (size_t)cb*512);
      bf16x8 bl = *(const bf16x8*)(bpl + (size_t)cb*512);
      acc[cb] = __builtin_amdgcn_mfma_f32_16x16x32_bf16(ah, bh, acc[cb], 0,0,0);
      acc[cb] = __builtin_amdgcn_mfma_f32_16x16x32_bf16(al, bh, acc[cb], 0,0,0);
      acc[cb] = __builtin_amdgcn_mfma_f32_16x16x32_bf16(ah, bl, acc[cb], 0,0,0);
    }
  }
  int crow = r0 + ((lane >> 4) << 2);
  int ccol = lane & 15;
  float rw[4] = {1.f,1.f,1.f,1.f};
  if (flags & 4){
#pragma unroll
    for (int r=0;r<4;r++) if (crow + r < M) rw[r] = rowscale[crow + r];
  }
  float* Yf = (float*)Yv;
  unsigned short* Yb = (unsigned short*)Yv;
#pragma unroll
  for (int cb=0; cb<NF; ++cb){
    int c = cb*16 + ccol;
    float b = bias[c];
    float sc = 1.f, sh = 0.f;
    if (flags & 1){ sc = scale[c]; sh = shift[c]; }
#pragma unroll
    for (int r=0;r<4;r++){
      int row = crow + r;
      if (row < M){
        float v = acc[cb][r] + b;
        if (flags & 1){ v = v*sc + sh; v = leakyf(v); }
        if (flags & 4) v *= rw[r];
        if (flags & 2) Yb[(size_t)row*Nn + c] = f32_to_bf16_rne(v);
        else           Yf[(size_t)row*Nn + c] = v;
      }
    }
  }
}

// ---------------- layer-0 aggregate fused with pair max-pool (dis folded in h0b) --------
__global__ __launch_bounds__(256) void mp0_kernel(
    const int* __restrict__ starts, const int* __restrict__ rs, const float* __restrict__ c0s,
    const float* __restrict__ dis0, const unsigned* __restrict__ h0b, const float* __restrict__ origin,
    const float* __restrict__ We, const float* __restrict__ be, float* __restrict__ xp, int N2)
{
  int p = blockIdx.x*4 + (threadIdx.x >> 6);
  if (p >= N2) return;
  int lane = threadIdx.x & 63;
  float wself = be[0];
#pragma unroll
  for (int i=0;i<12;i++) wself += We[i];
  int s = starts[p], e = starts[p+1];
  float axA = 0.f, ayA = 0.f, axB = 0.f, ayB = 0.f;
  int idx = s;
  for (; idx + 8 <= e; idx += 8){
    int rv[8]; float cf[8]; unsigned u[8];
#pragma unroll
    for (int j=0;j<8;j++){ rv[j] = rs[idx+j]; cf[j] = c0s[idx+j]; }
#pragma unroll
    for (int j=0;j<8;j++) u[j] = h0b[(size_t)(rv[j] & 0x7FFFFFFF)*64 + lane];
#pragma unroll
    for (int j=0;j<8;j++){
      float cB = (rv[j] < 0) ? cf[j] : 0.f;
      float cA = (rv[j] < 0) ? 0.f : cf[j];
      float lo = blo(u[j]), hi = bhi(u[j]);
      axA += cA*lo; ayA += cA*hi; axB += cB*lo; ayB += cB*hi;
    }
  }
  for (; idx < e; ++idx){
    int rv = rs[idx]; float cf = c0s[idx];
    unsigned u = h0b[(size_t)(rv & 0x7FFFFFFF)*64 + lane];
    float cB = (rv < 0) ? cf : 0.f;
    float cA = (rv < 0) ? 0.f : cf;
    float lo = blo(u), hi = bhi(u);
    axA += cA*lo; ayA += cA*hi; axB += cB*lo; ayB += cB*hi;
  }
  int nA = 2*p, nB = 2*p+1;
  float dnA = dis0[nA], dnB = dis0[nB];
  unsigned uA = h0b[(size_t)nA*64 + lane];
  unsigned uB = h0b[(size_t)nB*64 + lane];
  const float2 ogA = *(const float2*)(origin + (size_t)nA*128 + lane*2);
  const float2 ogB = *(const float2*)(origin + (size_t)nB*128 + lane*2);
  float oxA = leakyf(dnA*(axA + wself*blo(uA)) + ogA.x);
  float oyA = leakyf(dnA*(ayA + wself*bhi(uA)) + ogA.y);
  float oxB = leakyf(dnB*(axB + wself*blo(uB)) + ogB.x);
  float oyB = leakyf(dnB*(ayB + wself*bhi(uB)) + ogB.y);
  float2 o2 = {fmaxf(oxA, oxB), fmaxf(oyA, oyB)};
  *(float2*)(xp + (size_t)p*128 + lane*2) = o2;
}

// ---------------- layer-1 aggregate + global max pool (dis folded in h1b) ---------------
__global__ __launch_bounds__(256) void mp1_kernel(
    const int* __restrict__ starts, const int* __restrict__ rs, const float* __restrict__ c1s,
    const float* __restrict__ dis1, const unsigned* __restrict__ h1b,
    const float* __restrict__ We, const float* __restrict__ be,
    const int* __restrict__ batch_p, unsigned* __restrict__ genc, int N2)
{
  int n = blockIdx.x*4 + (threadIdx.x >> 6);
  if (n >= N2) return;
  int lane = threadIdx.x & 63;
  float wself = be[0];
#pragma unroll
  for (int i=0;i<12;i++) wself += We[i];
  int s = starts[n], e = starts[n+1];
  float dn = dis1[n];
  float ax = 0.f, ay = 0.f;
  int idx = s;
  for (; idx + 8 <= e; idx += 8){
    int rp[8]; float cf[8]; unsigned u[8];
#pragma unroll
    for (int j=0;j<8;j++){ rp[j] = (rs[idx+j] & 0x7FFFFFFF) >> 1; cf[j] = c1s[idx+j]; }
#pragma unroll
    for (int j=0;j<8;j++) u[j] = h1b[(size_t)rp[j]*64 + lane];
#pragma unroll
    for (int j=0;j<8;j++){
      float c = (rp[j] == n) ? 0.f : cf[j];
      ax += c * blo(u[j]);
      ay += c * bhi(u[j]);
    }
  }
  for (; idx < e; ++idx){
    int rp = (rs[idx] & 0x7FFFFFFF) >> 1;
    float c = (rp == n) ? 0.f : c1s[idx];
    unsigned u = h1b[(size_t)rp*64 + lane];
    ax += c * blo(u);
    ay += c * bhi(u);
  }
  unsigned us = h1b[(size_t)n*64 + lane];
  float ox = leakyf(dn*(ax + wself*blo(us)));
  float oy = leakyf(dn*(ay + wself*bhi(us)));
  int b = batch_p[n];
  atomicMax(&genc[(size_t)b*128 + lane*2    ], f32_ord(ox));
  atomicMax(&genc[(size_t)b*128 + lane*2 + 1], f32_ord(oy));
}

// ---------------- head MLP: [64,128] -> [64,64] -> [64] --------------------------------
__global__ __launch_bounds__(256) void head_kernel(
    const unsigned* __restrict__ genc, const float* __restrict__ W1, const float* __restrict__ b1,
    const float* __restrict__ s, const float* __restrict__ t,
    const float* __restrict__ W2, const float* __restrict__ b2, float* __restrict__ out)
{
  __shared__ float g[64][128];
  __shared__ float hh[64][64];
  int tid = threadIdx.x;
  for (int i = tid; i < 64*128; i += 256){
    unsigned u = genc[i];
    unsigned bits = (u & 0x80000000u) ? (u & 0x7FFFFFFFu) : ~u;
    g[i>>7][i&127] = __builtin_bit_cast(float, bits);
  }
  __syncthreads();
  int c = tid & 63;
  int q0 = tid >> 6;
  float accv[16];
#pragma unroll
  for (int i=0;i<16;i++) accv[i] = 0.f;
  for (int k=0;k<128;k++){
    float wv = W1[k*64 + c];
#pragma unroll
    for (int i=0;i<16;i++) accv[i] += g[q0*16+i][k] * wv;
  }
  float sc = s[c], sh = t[c], bb = b1[c];
#pragma unroll
  for (int i=0;i<16;i++){
    float v = (accv[i] + bb)*sc + sh;
    hh[q0*16+i][c] = leakyf(v);
  }
  __syncthreads();
  if (tid < 64){
    float a = b2[0];
    for (int k=0;k<64;k++) a += hh[tid][k]*W2[k];
    out[tid] = a;
  }
}

extern "C" void kernel_launch(void* const* d_in, const int* in_sizes, int n_in,
                              void* d_out, int out_size, void* d_ws, size_t ws_size,
                              hipStream_t stream)
{
  const float* x      = (const float*)d_in[0];
  const float* origin = (const float*)d_in[1];
  const float* ea     = (const float*)d_in[2];
  const int*   ei     = (const int*)d_in[3];
  const int*   batchp = (const int*)d_in[5];
  const float* l0_W1 = (const float*)d_in[6];
  const float* l0_b1 = (const float*)d_in[7];
  const float* l0_s  = (const float*)d_in[8];
  const float* l0_t  = (const float*)d_in[9];
  const float* l0_W2 = (const float*)d_in[10];
  const float* l0_b2 = (const float*)d_in[11];
  const float* l0_We = (const float*)d_in[12];
  const float* l0_be = (const float*)d_in[13];
  const float* l1_W1 = (const float*)d_in[14];
  const float* l1_b1 = (const float*)d_in[15];
  const float* l1_s  = (const float*)d_in[16];
  const float* l1_t  = (const float*)d_in[17];
  const float* l1_W2 = (const float*)d_in[18];
  const float* l1_b2 = (const float*)d_in[19];
  const float* l1_We = (const float*)d_in[20];
  const float* l1_be = (const float*)d_in[21];
  const float* hd_W1 = (const float*)d_in[22];
  const float* hd_b1 = (const float*)d_in[23];
  const float* hd_s  = (const float*)d_in[24];
  const float* hd_t  = (const float*)d_in[25];
  const float* hd_W2 = (const float*)d_in[26];
  const float* hd_b2 = (const float*)d_in[27];

  const int N  = in_sizes[0] / 128;   // 50000
  const int E  = in_sizes[2] / 12;    // 800000
  const int N2 = in_sizes[5];         // 25000
  const int G  = out_size;            // 64
  const int NB = (N2 + 255) / 256;    // scan blocks over pair bins

  char* ws = (char*)d_ws;
  size_t off = 0;
  auto alloc = [&](size_t b){ size_t o = off; off += (b + 255) & ~(size_t)255; return o; };
  size_t oA   = alloc((size_t)N*128*4);      // hmid0 / hmid1(25000x256)
  size_t oB   = alloc((size_t)N*128*4);      // [0,12.8M): h0b/h1b bf16 ; [12.8M,25.6M): xp f32
  size_t oRS  = alloc((size_t)E*4);
  size_t oC0  = alloc((size_t)E*4);
  size_t oC1  = alloc((size_t)E*4);
  size_t oRK  = alloc((size_t)E*2);
  size_t oST  = alloc((size_t)(N2+1)*4);
  size_t oBS  = alloc((size_t)NB*4);
  size_t zbytes = (size_t)N2*8*PKS + (size_t)G*128*4;
  size_t oZ   = alloc(zbytes);               // pk (padded) | genc
  size_t oPK  = oZ;
  size_t oGE  = oPK + (size_t)N2*8*PKS;
  size_t oD0  = alloc((size_t)N*4);
  size_t oD1  = alloc((size_t)N2*4);
  size_t oWsp = alloc((size_t)(16384*2 + 16384*2 + 32768*2 + 32768*2)*2);

  float* regA   = (float*)(ws + oA);
  unsigned* h0b = (unsigned*)(ws + oB);                  // 50000x128 bf16 (as uints)
  unsigned* h1b = (unsigned*)(ws + oB);                  // 25000x128 bf16 (h0b dead)
  float* xp     = (float*)(ws + oB + (size_t)N2*128*4);  // 25000x128 f32
  int*   rs     = (int*)(ws + oRS);
  float* c0s    = (float*)(ws + oC0);
  float* c1s    = (float*)(ws + oC1);
  unsigned short* rank = (unsigned short*)(ws + oRK);
  int*   starts = (int*)(ws + oST);
  int*   bsum   = (int*)(ws + oBS);
  unsigned long long* pk = (unsigned long long*)(ws + oPK);
  unsigned* genc= (unsigned*)(ws + oGE);
  float* dis0   = (float*)(ws + oD0);
  float* dis1   = (float*)(ws + oD1);
  short* l0W1h  = (short*)(ws + oWsp);
  short* l0W1l  = l0W1h + 16384;
  short* l0W2h  = l0W1l + 16384;
  short* l0W2l  = l0W2h + 16384;
  short* l1W1h  = l0W2l + 16384;
  short* l1W1l  = l1W1h + 32768;
  short* l1W2h  = l1W1l + 32768;
  short* l1W2l  = l1W2h + 32768;

  hipMemsetAsync(ws + oZ, 0, zbytes, stream);

  prep_w_kernel<<<64, 256, 0, stream>>>(l0_W1, l0W1h, l0W1l, 128, 128);
  prep_w_kernel<<<64, 256, 0, stream>>>(l0_W2, l0W2h, l0W2l, 128, 128);
  prep_w_kernel<<<128, 256, 0, stream>>>(l1_W1, l1W1h, l1W1l, 128, 256);
  prep_w_kernel<<<128, 256, 0, stream>>>(l1_W2, l1W2h, l1W2l, 256, 128);

  edge_hist_kernel<<<(E/4+255)/256, 256, 0, stream>>>(ei, pk, rank, E);
  dis_kernel<<<(N2+255)/256, 256, 0, stream>>>(pk, dis0, dis1, N2);
  scan_partial_kernel<<<NB, 256, 0, stream>>>(pk, bsum, N2);
  scan_bsums_kernel<<<1, 64, 0, stream>>>(bsum, NB);
  scan_final_kernel<<<NB, 256, 0, stream>>>(pk, bsum, starts, N2);
  fill_kernel<<<(E+255)/256, 256, 0, stream>>>(ei, ea, l0_We, l0_be, l1_We, l1_be,
                                               starts, rank, rs, c0s, c1s, E);

  // MLP0: x -> hmid0(regA) -> h0b (bf16, dis0-folded)
  gemm_split<8><<<(N+63)/64, 256, 0, stream>>>(x, l0W1h, l0W1l, l0_b1, l0_s, l0_t, nullptr, regA, N, 128, 1);
  gemm_split<8><<<(N+63)/64, 256, 0, stream>>>(regA, l0W2h, l0W2l, l0_b2, nullptr, nullptr, dis0, h0b, N, 128, 6);
  // aggregate layer0 fused with pair pool -> xp
  mp0_kernel<<<(N2+3)/4, 256, 0, stream>>>(starts, rs, c0s, dis0, h0b, origin, l0_We, l0_be, xp, N2);
  // MLP1: xp -> hmid1(regA, 25000x256) -> h1b (bf16, dis1-folded)
  gemm_split<16><<<(N2+63)/64, 256, 0, stream>>>(xp, l1W1h, l1W1l, l1_b1, l1_s, l1_t, nullptr, regA, N2, 128, 1);
  gemm_split<8><<<(N2+63)/64, 256, 0, stream>>>(regA, l1W2h, l1W2l, l1_b2, nullptr, nullptr, dis1, h1b, N2, 256, 6);
  // aggregate layer1 + global max pool
  mp1_kernel<<<(N2+3)/4, 256, 0, stream>>>(starts, rs, c1s, dis1, h1b, l1_We, l1_be, batchp, genc, N2);
  // head
  head_kernel<<<1, 256, 0, stream>>>(genc, hd_W1, hd_b1, hd_s, hd_t, hd_W2, hd_b2, (float*)d_out);
}

// Round 6
// 341.070 us; speedup vs baseline: 1.6346x; 1.0581x over previous
//
#include <hip/hip_runtime.h>

typedef __attribute__((ext_vector_type(4))) float f32x4;
typedef __attribute__((ext_vector_type(8))) short bf16x8;

#define NCH 25088   // static LDS bins (>= N2=25000)

__device__ __forceinline__ unsigned short f32_to_bf16_rne(float f){
  unsigned u = __builtin_bit_cast(unsigned, f);
  unsigned r = u + 0x7FFFu + ((u >> 16) & 1u);
  return (unsigned short)(r >> 16);
}
__device__ __forceinline__ float bf16_hi_to_f32(unsigned short h){
  unsigned u = ((unsigned)h) << 16;
  return __builtin_bit_cast(float, u);
}
__device__ __forceinline__ float blo(unsigned u){ return bf16_hi_to_f32((unsigned short)(u & 0xFFFF)); }
__device__ __forceinline__ float bhi(unsigned u){ return bf16_hi_to_f32((unsigned short)(u >> 16)); }
__device__ __forceinline__ float leakyf(float v){ return v > 0.f ? v : 0.01f*v; }
__device__ __forceinline__ unsigned f32_ord(float f){
  unsigned u = __builtin_bit_cast(unsigned, f);
  return (u & 0x80000000u) ? ~u : (u | 0x80000000u);
}

// ---------------- weight pre-split into MFMA B-fragment layout (hi/lo bf16) -------------
__global__ void prep_w_kernel(const float* __restrict__ W, short* __restrict__ Wh,
                              short* __restrict__ Wl, int K, int N)
{
  int total = K*N;
  int NF = N >> 4;
  for (int i = blockIdx.x*blockDim.x + threadIdx.x; i < total; i += gridDim.x*blockDim.x){
    int k = i / N, n = i % N;
    float w = W[i];
    unsigned short h = f32_to_bf16_rne(w);
    unsigned short l = f32_to_bf16_rne(w - bf16_hi_to_f32(h));
    int kb = k >> 5, kr = k & 31, cb = n >> 4;
    int lanei = ((kr >> 3) << 4) | (n & 15);
    size_t dst = (((size_t)(kb*NF + cb))*64 + lanei)*8 + (kr & 7);
    Wh[dst] = (short)h; Wl[dst] = (short)l;
  }
}

// ---------------- chunked col histogram: LDS atomics only, emits lrank + Hc ------------
__global__ __launch_bounds__(256) void col_chunk_kernel(const int* __restrict__ ei,
                                                        unsigned short* __restrict__ lrank,
                                                        unsigned short* __restrict__ Hc,
                                                        int E, int CS, int N2)
{
  __shared__ unsigned cnt[NCH];
  int tid = threadIdx.x;
  for (int i = tid; i < N2; i += 256) cnt[i] = 0;
  __syncthreads();
  int s = blockIdx.x*CS, eend = min(E, s + CS);
  for (int e = s + tid; e < eend; e += 256){
    int c = ei[E+e];
    unsigned lr = atomicAdd(&cnt[c>>1], 1u);
    lrank[e] = (unsigned short)lr;
  }
  __syncthreads();
  unsigned short* h = Hc + (size_t)blockIdx.x*N2;
  for (int i = tid; i < N2; i += 256) h[i] = (unsigned short)cnt[i];
}

// ---------------- chunked row histogram: packed even|odd, sparse intra atomics ---------
__global__ __launch_bounds__(256) void row_chunk_kernel(const int* __restrict__ ei,
                                                        unsigned* __restrict__ RH,
                                                        unsigned* __restrict__ intra,
                                                        int E, int CS, int N2)
{
  __shared__ unsigned cnt[NCH];
  int tid = threadIdx.x;
  for (int i = tid; i < N2; i += 256) cnt[i] = 0;
  __syncthreads();
  int s = blockIdx.x*CS, eend = min(E, s + CS);
  for (int e = s + tid; e < eend; e += 256){
    int r = ei[e], c = ei[E+e];
    atomicAdd(&cnt[r>>1], (r & 1) ? 0x10000u : 1u);
    if ((r>>1) == (c>>1)) atomicAdd(&intra[r>>1], 1u);   // ~E/N2 edges total: negligible
  }
  __syncthreads();
  unsigned* h = RH + (size_t)blockIdx.x*N2;
  for (int i = tid; i < N2; i += 256) h[i] = cnt[i];
}

// ---------------- per-bin chunk-offset prefix + bin totals -----------------------------
__global__ void co_scan_kernel(const unsigned short* __restrict__ Hc,
                               unsigned short* __restrict__ CO,
                               int* __restrict__ colTotal, int N2)
{
  int bin = blockIdx.x*blockDim.x + threadIdx.x;
  if (bin >= N2) return;
  unsigned acc = 0;
#pragma unroll
  for (int ch = 0; ch < 64; ++ch){
    CO[(size_t)ch*N2 + bin] = (unsigned short)acc;
    acc += Hc[(size_t)ch*N2 + bin];
  }
  colTotal[bin] = (int)acc;
}

// ---------------- dis from chunked row histograms --------------------------------------
__global__ void dis_kernel(const unsigned* __restrict__ RH, const unsigned* __restrict__ intra,
                           float* __restrict__ dis0, float* __restrict__ dis1, int N2)
{
  int p = blockIdx.x*blockDim.x + threadIdx.x;
  if (p >= N2) return;
  unsigned se = 0, so = 0;
#pragma unroll
  for (int ch = 0; ch < 64; ++ch){
    unsigned v = RH[(size_t)ch*N2 + p];
    se += v & 0xFFFFu; so += v >> 16;
  }
  float2 d0 = { rsqrtf((float)se + 1.0f), rsqrtf((float)so + 1.0f) };
  *(float2*)(dis0 + 2*p) = d0;
  dis1[p] = rsqrtf((float)(se + so - intra[p]) + 1.0f);
}

// ---------------- 3-pass parallel exclusive scan over colTotal -------------------------
__global__ void scan_partial_kernel(const int* __restrict__ cnt, int* __restrict__ bsum, int N)
{
  __shared__ int ws[4];
  int t = threadIdx.x, lane = t & 63, wv = t >> 6;
  int i = blockIdx.x*256 + t;
  int v = (i < N) ? cnt[i] : 0;
#pragma unroll
  for (int d = 1; d < 64; d <<= 1) v += __shfl_xor(v, d);
  if (lane == 0) ws[wv] = v;
  __syncthreads();
  if (t == 0) bsum[blockIdx.x] = ws[0]+ws[1]+ws[2]+ws[3];
}

__global__ void scan_bsums_kernel(int* __restrict__ bsum, int NB)
{
  int lane = threadIdx.x;  // 64 threads, 1 wave
  int carry = 0;
  for (int base = 0; base < NB; base += 64){
    int i = base + lane;
    int v = (i < NB) ? bsum[i] : 0;
    int x = v;
#pragma unroll
    for (int d = 1; d < 64; d <<= 1){
      int y = __shfl_up(x, d);
      if (lane >= d) x += y;
    }
    if (i < NB) bsum[i] = x - v + carry;   // exclusive
    carry += __shfl(x, 63);
  }
}

__global__ void scan_final_kernel(const int* __restrict__ cnt, const int* __restrict__ bsum,
                                  int* __restrict__ starts, int N)
{
  __shared__ int wsum[4];
  int t = threadIdx.x, lane = t & 63, wv = t >> 6;
  int i = blockIdx.x*256 + t;
  int v = (i < N) ? cnt[i] : 0;
  int x = v;
#pragma unroll
  for (int d = 1; d < 64; d <<= 1){
    int y = __shfl_up(x, d);
    if (lane >= d) x += y;
  }
  if (lane == 63) wsum[wv] = x;
  __syncthreads();
  int woff = 0;
#pragma unroll
  for (int j = 0; j < 4; j++) if (j < wv) woff += wsum[j];
  int base = bsum[blockIdx.x] + woff;
  if (i < N) starts[i+1] = base + x;
  if (blockIdx.x == 0 && t == 0) starts[0] = 0;
}

// ---------------- CSR fill: atomic-free via lrank + chunk offsets ----------------------
__global__ void fill_kernel(const int* __restrict__ ei, const float* __restrict__ ea,
                            const float* __restrict__ We0, const float* __restrict__ be0,
                            const float* __restrict__ We1, const float* __restrict__ be1,
                            const int* __restrict__ starts,
                            const unsigned short* __restrict__ lrank,
                            const unsigned short* __restrict__ CO,
                            int* __restrict__ rs,
                            float* __restrict__ c0s, float* __restrict__ c1s,
                            int E, int CS, int N2)
{
  float A0[12], A1[12];
#pragma unroll
  for (int i=0;i<12;i++){ A0[i]=We0[i]; A1[i]=We1[i]; }
  float b0 = be0[0], b1 = be1[0];
  int e = blockIdx.x*blockDim.x + threadIdx.x;
  if (e >= E) return;
  int r = ei[e], c = ei[E+e];
  const f32x4* ap = (const f32x4*)(ea + (size_t)e*12);
  f32x4 v0 = ap[0], v1 = ap[1], v2 = ap[2];
  float s0 = b0, s1 = b1;
#pragma unroll
  for (int j=0;j<4;j++){ s0 += v0[j]*A0[j];   s1 += v0[j]*A1[j]; }
#pragma unroll
  for (int j=0;j<4;j++){ s0 += v1[j]*A0[4+j]; s1 += v1[j]*A1[4+j]; }
#pragma unroll
  for (int j=0;j<4;j++){ s0 += v2[j]*A0[8+j]; s1 += v2[j]*A1[8+j]; }
  int bin = c >> 1;
  int ch  = e / CS;
  int pos = starts[bin] + (int)CO[(size_t)ch*N2 + bin] + (int)lrank[e];
  rs[pos]  = r | ((c & 1) << 31);
  c0s[pos] = s0;
  c1s[pos] = s1;
}

// ---------------- split-bf16 MFMA GEMM: Y = epilogue(X @ W + b) -------------------------
// flags&1: y = leaky(y*scale + shift);  flags&2: store bf16;  flags&4: y *= rowscale[row]
template<int NF>
__global__ __launch_bounds__(256) void gemm_split(
    const float* __restrict__ X, const short* __restrict__ Wh, const short* __restrict__ Wl,
    const float* __restrict__ bias, const float* __restrict__ scale, const float* __restrict__ shift,
    const float* __restrict__ rowscale,
    void* __restrict__ Yv, int M, int K, int flags)
{
  const int Nn = NF*16;
  int w = threadIdx.x >> 6, lane = threadIdx.x & 63;
  int r0 = blockIdx.x*64 + w*16;
  int arow = r0 + (lane & 15);
  long arow_c = (arow < M) ? arow : (M-1);
  int kHi = (lane >> 4) << 3;
  f32x4 acc[NF];
#pragma unroll
  for (int i=0;i<NF;i++){
#pragma unroll
    for (int j=0;j<4;j++) acc[i][j] = 0.f;
  }
  int KB = K >> 5;
  const float* aprow = X + arow_c*(long)K + kHi;
  for (int kb=0; kb<KB; ++kb){
    const float* ap = aprow + kb*32;
    f32x4 a0 = *(const f32x4*)ap;
    f32x4 a1 = *(const f32x4*)(ap+4);
    bf16x8 ah, al;
#pragma unroll
    for (int j=0;j<8;j++){
      float f = (j<4) ? a0[j] : a1[j-4];
      unsigned short h = f32_to_bf16_rne(f);
      ah[j] = (short)h;
      al[j] = (short)f32_to_bf16_rne(f - bf16_hi_to_f32(h));
    }
    const short* bp  = Wh + ((size_t)kb*NF*64 + lane)*8;
    const short* bpl = Wl + ((size_t)kb*NF*64 + lane)*8;
#pragma unroll
    for (int cb=0; cb<NF; ++cb){
      bf16x8 bh = *(const bf16x8*)(bp  + (size_t)cb*512);
      bf16x8 bl = *(const bf16x8*)(bpl + (size_t)cb*512);
      acc[cb] = __builtin_amdgcn_mfma_f32_16x16x32_bf16(ah, bh, acc[cb], 0,0,0);
      acc[cb] = __builtin_amdgcn_mfma_f32_16x16x32_bf16(al, bh, acc[cb], 0,0,0);
      acc[cb] = __builtin_amdgcn_mfma_f32_16x16x32_bf16(ah, bl, acc[cb], 0,0,0);
    }
  }
  int crow = r0 + ((lane >> 4) << 2);
  int ccol = lane & 15;
  float rw[4] = {1.f,1.f,1.f,1.f};
  if (flags & 4){
#pragma unroll
    for (int r=0;r<4;r++) if (crow + r < M) rw[r] = rowscale[crow + r];
  }
  float* Yf = (float*)Yv;
  unsigned short* Yb = (unsigned short*)Yv;
#pragma unroll
  for (int cb=0; cb<NF; ++cb){
    int c = cb*16 + ccol;
    float b = bias[c];
    float sc = 1.f, sh = 0.f;
    if (flags & 1){ sc = scale[c]; sh = shift[c]; }
#pragma unroll
    for (int r=0;r<4;r++){
      int row = crow + r;
      if (row < M){
        float v = acc[cb][r] + b;
        if (flags & 1){ v = v*sc + sh; v = leakyf(v); }
        if (flags & 4) v *= rw[r];
        if (flags & 2) Yb[(size_t)row*Nn + c] = f32_to_bf16_rne(v);
        else           Yf[(size_t)row*Nn + c] = v;
      }
    }
  }
}

// ---------------- layer-0 aggregate fused with pair max-pool (dis folded in h0b) --------
__global__ __launch_bounds__(256) void mp0_kernel(
    const int* __restrict__ starts, const int* __restrict__ rs, const float* __restrict__ c0s,
    const float* __restrict__ dis0, const unsigned* __restrict__ h0b, const float* __restrict__ origin,
    const float* __restrict__ We, const float* __restrict__ be, float* __restrict__ xp, int N2)
{
  int p = blockIdx.x*4 + (threadIdx.x >> 6);
  if (p >= N2) return;
  int lane = threadIdx.x & 63;
  float wself = be[0];
#pragma unroll
  for (int i=0;i<12;i++) wself += We[i];
  int s = starts[p], e = starts[p+1];
  float axA = 0.f, ayA = 0.f, axB = 0.f, ayB = 0.f;
  int idx = s;
  for (; idx + 8 <= e; idx += 8){
    int rv[8]; float cf[8]; unsigned u[8];
#pragma unroll
    for (int j=0;j<8;j++){ rv[j] = rs[idx+j]; cf[j] = c0s[idx+j]; }
#pragma unroll
    for (int j=0;j<8;j++) u[j] = h0b[(size_t)(rv[j] & 0x7FFFFFFF)*64 + lane];
#pragma unroll
    for (int j=0;j<8;j++){
      float cB = (rv[j] < 0) ? cf[j] : 0.f;
      float cA = (rv[j] < 0) ? 0.f : cf[j];
      float lo = blo(u[j]), hi = bhi(u[j]);
      axA += cA*lo; ayA += cA*hi; axB += cB*lo; ayB += cB*hi;
    }
  }
  for (; idx < e; ++idx){
    int rv = rs[idx]; float cf = c0s[idx];
    unsigned u = h0b[(size_t)(rv & 0x7FFFFFFF)*64 + lane];
    float cB = (rv < 0) ? cf : 0.f;
    float cA = (rv < 0) ? 0.f : cf;
    float lo = blo(u), hi = bhi(u);
    axA += cA*lo; ayA += cA*hi; axB += cB*lo; ayB += cB*hi;
  }
  int nA = 2*p, nB = 2*p+1;
  float dnA = dis0[nA], dnB = dis0[nB];
  unsigned uA = h0b[(size_t)nA*64 + lane];
  unsigned uB = h0b[(size_t)nB*64 + lane];
  const float2 ogA = *(const float2*)(origin + (size_t)nA*128 + lane*2);
  const float2 ogB = *(const float2*)(origin + (size_t)nB*128 + lane*2);
  float oxA = leakyf(dnA*(axA + wself*blo(uA)) + ogA.x);
  float oyA = leakyf(dnA*(ayA + wself*bhi(uA)) + ogA.y);
  float oxB = leakyf(dnB*(axB + wself*blo(uB)) + ogB.x);
  float oyB = leakyf(dnB*(ayB + wself*bhi(uB)) + ogB.y);
  float2 o2 = {fmaxf(oxA, oxB), fmaxf(oyA, oyB)};
  *(float2*)(xp + (size_t)p*128 + lane*2) = o2;
}

// ---------------- layer-1 aggregate + global max pool (dis folded in h1b) ---------------
__global__ __launch_bounds__(256) void mp1_kernel(
    const int* __restrict__ starts, const int* __restrict__ rs, const float* __restrict__ c1s,
    const float* __restrict__ dis1, const unsigned* __restrict__ h1b,
    const float* __restrict__ We, const float* __restrict__ be,
    const int* __restrict__ batch_p, unsigned* __restrict__ genc, int N2)
{
  int n = blockIdx.x*4 + (threadIdx.x >> 6);
  if (n >= N2) return;
  int lane = threadIdx.x & 63;
  float wself = be[0];
#pragma unroll
  for (int i=0;i<12;i++) wself += We[i];
  int s = starts[n], e = starts[n+1];
  float dn = dis1[n];
  float ax = 0.f, ay = 0.f;
  int idx = s;
  for (; idx + 8 <= e; idx += 8){
    int rp[8]; float cf[8]; unsigned u[8];
#pragma unroll
    for (int j=0;j<8;j++){ rp[j] = (rs[idx+j] & 0x7FFFFFFF) >> 1; cf[j] = c1s[idx+j]; }
#pragma unroll
    for (int j=0;j<8;j++) u[j] = h1b[(size_t)rp[j]*64 + lane];
#pragma unroll
    for (int j=0;j<8;j++){
      float c = (rp[j] == n) ? 0.f : cf[j];
      ax += c * blo(u[j]);
      ay += c * bhi(u[j]);
    }
  }
  for (; idx < e; ++idx){
    int rp = (rs[idx] & 0x7FFFFFFF) >> 1;
    float c = (rp == n) ? 0.f : c1s[idx];
    unsigned u = h1b[(size_t)rp*64 + lane];
    ax += c * blo(u);
    ay += c * bhi(u);
  }
  unsigned us = h1b[(size_t)n*64 + lane];
  float ox = leakyf(dn*(ax + wself*blo(us)));
  float oy = leakyf(dn*(ay + wself*bhi(us)));
  int b = batch_p[n];
  atomicMax(&genc[(size_t)b*128 + lane*2    ], f32_ord(ox));
  atomicMax(&genc[(size_t)b*128 + lane*2 + 1], f32_ord(oy));
}

// ---------------- head MLP: [64,128] -> [64,64] -> [64] --------------------------------
__global__ __launch_bounds__(256) void head_kernel(
    const unsigned* __restrict__ genc, const float* __restrict__ W1, const float* __restrict__ b1,
    const float* __restrict__ s, const float* __restrict__ t,
    const float* __restrict__ W2, const float* __restrict__ b2, float* __restrict__ out)
{
  __shared__ float g[64][128];
  __shared__ float hh[64][64];
  int tid = threadIdx.x;
  for (int i = tid; i < 64*128; i += 256){
    unsigned u = genc[i];
    unsigned bits = (u & 0x80000000u) ? (u & 0x7FFFFFFFu) : ~u;
    g[i>>7][i&127] = __builtin_bit_cast(float, bits);
  }
  __syncthreads();
  int c = tid & 63;
  int q0 = tid >> 6;
  float accv[16];
#pragma unroll
  for (int i=0;i<16;i++) accv[i] = 0.f;
  for (int k=0;k<128;k++){
    float wv = W1[k*64 + c];
#pragma unroll
    for (int i=0;i<16;i++) accv[i] += g[q0*16+i][k] * wv;
  }
  float sc = s[c], sh = t[c], bb = b1[c];
#pragma unroll
  for (int i=0;i<16;i++){
    float v = (accv[i] + bb)*sc + sh;
    hh[q0*16+i][c] = leakyf(v);
  }
  __syncthreads();
  if (tid < 64){
    float a = b2[0];
    for (int k=0;k<64;k++) a += hh[tid][k]*W2[k];
    out[tid] = a;
  }
}

extern "C" void kernel_launch(void* const* d_in, const int* in_sizes, int n_in,
                              void* d_out, int out_size, void* d_ws, size_t ws_size,
                              hipStream_t stream)
{
  const float* x      = (const float*)d_in[0];
  const float* origin = (const float*)d_in[1];
  const float* ea     = (const float*)d_in[2];
  const int*   ei     = (const int*)d_in[3];
  const int*   batchp = (const int*)d_in[5];
  const float* l0_W1 = (const float*)d_in[6];
  const float* l0_b1 = (const float*)d_in[7];
  const float* l0_s  = (const float*)d_in[8];
  const float* l0_t  = (const float*)d_in[9];
  const float* l0_W2 = (const float*)d_in[10];
  const float* l0_b2 = (const float*)d_in[11];
  const float* l0_We = (const float*)d_in[12];
  const float* l0_be = (const float*)d_in[13];
  const float* l1_W1 = (const float*)d_in[14];
  const float* l1_b1 = (const float*)d_in[15];
  const float* l1_s  = (const float*)d_in[16];
  const float* l1_t  = (const float*)d_in[17];
  const float* l1_W2 = (const float*)d_in[18];
  const float* l1_b2 = (const float*)d_in[19];
  const float* l1_We = (const float*)d_in[20];
  const float* l1_be = (const float*)d_in[21];
  const float* hd_W1 = (const float*)d_in[22];
  const float* hd_b1 = (const float*)d_in[23];
  const float* hd_s  = (const float*)d_in[24];
  const float* hd_t  = (const float*)d_in[25];
  const float* hd_W2 = (const float*)d_in[26];
  const float* hd_b2 = (const float*)d_in[27];

  const int N  = in_sizes[0] / 128;   // 50000
  const int E  = in_sizes[2] / 12;    // 800000
  const int N2 = in_sizes[5];         // 25000
  const int G  = out_size;            // 64
  const int NB = (N2 + 255) / 256;    // scan blocks over pair bins
  const int CS = (E + 63) / 64;       // edges per chunk (64 chunks)

  char* ws = (char*)d_ws;
  size_t off = 0;
  auto alloc = [&](size_t b){ size_t o = off; off += (b + 255) & ~(size_t)255; return o; };
  size_t oA   = alloc((size_t)N*128*4);      // pre-GEMM: Hc|RH|CO|colTotal ; then hmid0/hmid1
  size_t oB   = alloc((size_t)N*128*4);      // [0,12.8M): h0b/h1b bf16 ; [12.8M,25.6M): xp f32
  size_t oRS  = alloc((size_t)E*4);
  size_t oC0  = alloc((size_t)E*4);
  size_t oC1  = alloc((size_t)E*4);
  size_t oRK  = alloc((size_t)E*2);
  size_t oST  = alloc((size_t)(N2+1)*4);
  size_t oBS  = alloc((size_t)NB*4);
  size_t zbytes = (size_t)N2*4 + (size_t)G*128*4;
  size_t oZ   = alloc(zbytes);               // intra | genc
  size_t oIN  = oZ;
  size_t oGE  = oIN + (size_t)N2*4;
  size_t oD0  = alloc((size_t)N*4);
  size_t oD1  = alloc((size_t)N2*4);
  size_t oWsp = alloc((size_t)(16384*2 + 16384*2 + 32768*2 + 32768*2)*2);

  float* regA   = (float*)(ws + oA);
  // chunked-histogram scratch lives inside oA (dead before first GEMM writes regA)
  size_t aoff = oA;
  auto suballoc = [&](size_t b){ size_t o = aoff; aoff += (b + 255) & ~(size_t)255; return o; };
  unsigned short* Hc = (unsigned short*)(ws + suballoc((size_t)64*N2*2));
  unsigned*       RH = (unsigned*)      (ws + suballoc((size_t)64*N2*4));
  unsigned short* CO = (unsigned short*)(ws + suballoc((size_t)64*N2*2));
  int*      colTotal = (int*)           (ws + suballoc((size_t)N2*4));

  unsigned* h0b = (unsigned*)(ws + oB);                  // 50000x128 bf16 (as uints)
  unsigned* h1b = (unsigned*)(ws + oB);                  // 25000x128 bf16 (h0b dead)
  float* xp     = (float*)(ws + oB + (size_t)N2*128*4);  // 25000x128 f32
  int*   rs     = (int*)(ws + oRS);
  float* c0s    = (float*)(ws + oC0);
  float* c1s    = (float*)(ws + oC1);
  unsigned short* lrank = (unsigned short*)(ws + oRK);
  int*   starts = (int*)(ws + oST);
  int*   bsum   = (int*)(ws + oBS);
  unsigned* intra = (unsigned*)(ws + oIN);
  unsigned* genc= (unsigned*)(ws + oGE);
  float* dis0   = (float*)(ws + oD0);
  float* dis1   = (float*)(ws + oD1);
  short* l0W1h  = (short*)(ws + oWsp);
  short* l0W1l  = l0W1h + 16384;
  short* l0W2h  = l0W1l + 16384;
  short* l0W2l  = l0W2h + 16384;
  short* l1W1h  = l0W2l + 16384;
  short* l1W1l  = l1W1h + 32768;
  short* l1W2h  = l1W1l + 32768;
  short* l1W2l  = l1W2h + 32768;

  hipMemsetAsync(ws + oZ, 0, zbytes, stream);

  prep_w_kernel<<<64, 256, 0, stream>>>(l0_W1, l0W1h, l0W1l, 128, 128);
  prep_w_kernel<<<64, 256, 0, stream>>>(l0_W2, l0W2h, l0W2l, 128, 128);
  prep_w_kernel<<<128, 256, 0, stream>>>(l1_W1, l1W1h, l1W1l, 128, 256);
  prep_w_kernel<<<128, 256, 0, stream>>>(l1_W2, l1W2h, l1W2l, 256, 128);

  col_chunk_kernel<<<64, 256, 0, stream>>>(ei, lrank, Hc, E, CS, N2);
  row_chunk_kernel<<<64, 256, 0, stream>>>(ei, RH, intra, E, CS, N2);
  co_scan_kernel<<<(N2+255)/256, 256, 0, stream>>>(Hc, CO, colTotal, N2);
  dis_kernel<<<(N2+255)/256, 256, 0, stream>>>(RH, intra, dis0, dis1, N2);
  scan_partial_kernel<<<NB, 256, 0, stream>>>(colTotal, bsum, N2);
  scan_bsums_kernel<<<1, 64, 0, stream>>>(bsum, NB);
  scan_final_kernel<<<NB, 256, 0, stream>>>(colTotal, bsum, starts, N2);
  fill_kernel<<<(E+255)/256, 256, 0, stream>>>(ei, ea, l0_We, l0_be, l1_We, l1_be,
                                               starts, lrank, CO, rs, c0s, c1s, E, CS, N2);

  // MLP0: x -> hmid0(regA) -> h0b (bf16, dis0-folded)
  gemm_split<8><<<(N+63)/64, 256, 0, stream>>>(x, l0W1h, l0W1l, l0_b1, l0_s, l0_t, nullptr, regA, N, 128, 1);
  gemm_split<8><<<(N+63)/64, 256, 0, stream>>>(regA, l0W2h, l0W2l, l0_b2, nullptr, nullptr, dis0, h0b, N, 128, 6);
  // aggregate layer0 fused with pair pool -> xp
  mp0_kernel<<<(N2+3)/4, 256, 0, stream>>>(starts, rs, c0s, dis0, h0b, origin, l0_We, l0_be, xp, N2);
  // MLP1: xp -> hmid1(regA, 25000x256) -> h1b (bf16, dis1-folded)
  gemm_split<16><<<(N2+63)/64, 256, 0, stream>>>(xp, l1W1h, l1W1l, l1_b1, l1_s, l1_t, nullptr, regA, N2, 128, 1);
  gemm_split<8><<<(N2+63)/64, 256, 0, stream>>>(regA, l1W2h, l1W2l, l1_b2, nullptr, nullptr, dis1, h1b, N2, 256, 6);
  // aggregate layer1 + global max pool
  mp1_kernel<<<(N2+3)/4, 256, 0, stream>>>(starts, rs, c1s, dis1, h1b, l1_We, l1_be, batchp, genc, N2);
  // head
  head_kernel<<<1, 256, 0, stream>>>(genc, hd_W1, hd_b1, hd_s, hd_t, hd_W2, hd_b2, (float*)d_out);
}